// Round 12
// baseline (1328.525 us; speedup 1.0000x reference)
//
#include <hip/hip_runtime.h>
#include <math.h>

typedef _Float16 h8 __attribute__((ext_vector_type(8)));
typedef float f4 __attribute__((ext_vector_type(4)));

// ---------------------------------------------------------------------------
// Workspace layout (float units). All activations NHWC f16 with spatial HALO
// (zero-filled) so conv/sim gathers need no bounds checks. Peak ~163 MB.
// Scale chain: sims stored x2^-10, r1 dsc=1024; regressor acts x1/64,
// consumers dsc=64; k_final x64. All pow2 (exact).
// ---------------------------------------------------------------------------
static const size_t OFF_SIMSH = 256;       // (6, 64x64, 8) h halo8 = 98304 fl
static const size_t OFF_WB    = 98560;     // weight banks, 6895616 h
static const size_t ARENA     = 3546368;
// phase 1
static const size_t IMH  = 3546368;    // (2,400x400,8) h halo8
static const size_t B1H  = 4826368;    // (2,208x208,64) halo8
static const size_t B2H  = 7595264;    // (2,112x112,256) halo8
static const size_t F3H  = 10806528;   // (2,72x72,512) halo12
static const size_t F4H  = 13460736;   // (2,48x48,1024) halo12
static const size_t PRAW = 15820032;   // fp32 2359296
static const size_t PSC  = 18179328;   // fp32 8957952
static const size_t SIMRAW = 27137280; // fp32 51840
static const size_t WSIM = 27189120;   // f16 15925248 h -> end 35151744
// phase 2 (reuses arena after k_sims)
static const size_t R1H = 3546368;     // (6,64x64,200) halo8
static const size_t U1H = 6003968;     // (6,112x112,200) halo8
static const size_t R2H = 13530368;    // (6,96x96,128) no halo
static const size_t U2H = 17069312;    // (6,208x208,128) halo8
static const size_t R3H = 33676544;    // (6,192x192,64) no halo -> end 40754432

// f16-unit offsets inside WB bank
static const size_t WB1 = 0;          // 52kq x 64
static const size_t WB2 = 26624;      // 72 x 256
static const size_t WB3 = 174080;     // 288 x 512
static const size_t WB4 = 1353728;    // 576 x 1024
static const size_t WR1 = 6072320;    // 52 x 256
static const size_t WR2 = 6178816;    // 628 x 128
static const size_t WR3 = 6821888;    // 144 x 64

// ---------------------------------------------------------------------------
__global__ __launch_bounds__(64) void k_meta(const float* __restrict__ tlbrs,
                                             int* __restrict__ meta)
{
    if (threadIdx.x != 0 || blockIdx.x != 0) return;
    const double SC[3] = {1.0, 0.9, 1.1};
    for (int b = 0; b < 2; ++b)
        for (int lvl = 0; lvl < 2; ++lvl) {
            int FH = lvl ? 24 : 48;
            float scaling = lvl ? 16.f : 8.f;
            int base = (b * 2 + lvl) * 32;
            int PH = 0, PW = 0;
            for (int p = 0; p < 3; ++p) {
                const float* t4 = tlbrs + (b * 3 + p) * 4;
                float st = t4[0] / scaling, sl = t4[1] / scaling;
                float sb = t4[2] / scaling, sr = t4[3] / scaling;
                int top  = (int)fmaxf(floorf(st), 0.f);
                int left = (int)fmaxf(floorf(sl), 0.f);
                int bot  = (int)fminf(ceilf(sb) + 1.f, (float)FH);
                int rgt  = (int)fminf(ceilf(sr) + 1.f, (float)FH);
                meta[base + p * 4 + 0] = top;
                meta[base + p * 4 + 1] = left;
                meta[base + p * 4 + 2] = bot;
                meta[base + p * 4 + 3] = rgt;
                PH = max(PH, bot - top);
                PW = max(PW, rgt - left);
            }
            meta[base + 12] = PH;
            meta[base + 13] = PW;
            for (int s = 0; s < 3; ++s) {
                int PHs = (int)ceil((double)PH * SC[s]);
                int PWs = (int)ceil((double)PW * SC[s]);
                if (PHs < 1) PHs = PH;
                if (PWs < 1) PWs = PW;
                meta[base + 14 + s * 2] = PHs;
                meta[base + 15 + s * 2] = PWs;
            }
        }
}

// ---------------------------------------------------------------------------
// Zero the halo frames (ws is re-poisoned each launch).
// ---------------------------------------------------------------------------
__device__ __forceinline__ void halo_zero(h8* base, int Hp, int Wp, int halo,
                                          int Cg, int N)
{
    int inner = Hp - 2 * halo;
    int frame = Hp * Wp - inner * inner;
    long total = (long)N * frame * Cg;
    long idx = (long)blockIdx.x * 256 + threadIdx.x;
    if (idx >= total) return;
    int cg = (int)(idx % Cg);
    long r = idx / Cg;
    int f = (int)(r % frame);
    int n = (int)(r / frame);
    int topN = halo * Wp;
    int y, x;
    if (f < topN) { y = f / Wp; x = f % Wp; }
    else if (f < 2 * topN) { int f2 = f - topN; y = Hp - halo + f2 / Wp; x = f2 % Wp; }
    else {
        int f3 = f - 2 * topN;
        int row = f3 / (2 * halo), rr = f3 - row * (2 * halo);
        y = halo + row;
        x = rr < halo ? rr : Wp - 2 * halo + rr;
    }
    h8 z;
#pragma unroll
    for (int j = 0; j < 8; ++j) z[j] = (_Float16)0.f;
    base[((long)n * Hp * Wp + (long)y * Wp + x) * Cg + cg] = z;
}

__global__ __launch_bounds__(256) void k_halos1(float* wsf)
{
    switch (blockIdx.y) {
    case 0: halo_zero((h8*)(wsf + IMH), 400, 400, 8, 1, 2); break;
    case 1: halo_zero((h8*)(wsf + B1H), 208, 208, 8, 8, 2); break;
    case 2: halo_zero((h8*)(wsf + B2H), 112, 112, 8, 32, 2); break;
    case 3: halo_zero((h8*)(wsf + F3H), 72, 72, 12, 64, 2); break;
    default: halo_zero((h8*)(wsf + F4H), 48, 48, 12, 128, 2); break;
    }
}

__global__ __launch_bounds__(256) void k_halos2(float* wsf)
{
    switch (blockIdx.y) {
    case 0: halo_zero((h8*)(wsf + OFF_SIMSH), 64, 64, 8, 1, 6); break;
    case 1: halo_zero((h8*)(wsf + R1H), 64, 64, 8, 25, 6); break;
    case 2: halo_zero((h8*)(wsf + U1H), 112, 112, 8, 25, 6); break;
    default: halo_zero((h8*)(wsf + U2H), 208, 208, 8, 16, 6); break;
    }
}

// ---------------------------------------------------------------------------
// images NCHW fp32 -> NHWC f16 interior of halo-padded (400x400)
// ---------------------------------------------------------------------------
__global__ __launch_bounds__(256) void k_im2hwc(const float* __restrict__ img,
    _Float16* __restrict__ o)
{
    int idx = blockIdx.x * 256 + threadIdx.x;
    if (idx >= 2359296) return;
    int c = idx & 7;
    int pix = (idx >> 3) % 147456;
    int b = (idx >> 3) / 147456;
    int y = pix / 384, x = pix - y * 384;
    float v = (c < 3) ? img[((size_t)b * 3 + c) * 147456 + pix] : 0.f;
    o[((size_t)b * 1280000 + ((size_t)(y + 8) * 400 + (x + 8)) * 8) + c] = (_Float16)v;
}

// ---------------------------------------------------------------------------
__global__ __launch_bounds__(256) void k_wprepH(const float* __restrict__ w,
    _Float16* __restrict__ wB, int Cin, int KKt, int Cinp, int Cout, int Coutp,
    int total)
{
    int idx = blockIdx.x * 256 + threadIdx.x;
    if (idx >= total) return;
    int j = idx & 7;
    int co = (idx >> 3) % Coutp;
    int kq = idx / (8 * Coutp);
    int k = kq * 8 + j;
    int tap = k / Cinp, cip = k - tap * Cinp;
    float v = 0.f;
    if (tap < KKt && cip < Cin && co < Cout)
        v = w[((size_t)co * Cin + cip) * KKt + tap];
    wB[idx] = (_Float16)v;
}

// ---------------------------------------------------------------------------
// Halo NHWC implicit-GEMM conv: no bounds checks anywhere in the K-loop.
// inI/outI are interior pointers; Winp/Wop padded row strides. Requires
// M % (MT*32) == 0 and halo covering pad + tap-overshoot (wB zero-padded).
// Software-pipelined depth 1, LDS-free, f16 MFMA 16x16x32 fp32 accum.
// ---------------------------------------------------------------------------
template<int KK, int KW, int S, int CINP, int MT>
__global__ __launch_bounds__(256) void k_convH(
    const _Float16* __restrict__ inI, int Winp, long inStride,
    const _Float16* __restrict__ wB, const float* __restrict__ bias,
    _Float16* __restrict__ outI, int Wop, long outStride,
    int Cout, int Coutp, int Wout, int pad, int Kpad, int storeC,
    float dsc, float osc)
{
    const int tid = threadIdx.x;
    const int n_img = blockIdx.z;
    const int m0 = blockIdx.x * (MT * 32);
    const int co0 = blockIdx.y * 64;
    const _Float16* inb = inI + (size_t)n_img * inStride;

    const int wv = tid >> 6, lane = tid & 63;
    const int wr = wv & 1, wc = wv >> 1;
    const int lq = lane >> 4, lr = lane & 15;

    const _Float16* pb[MT];
#pragma unroll
    for (int mt = 0; mt < MT; ++mt) {
        int m = m0 + (wr * MT + mt) * 16 + lr;
        int y = m / Wout, x = m - y * Wout;
        pb[mt] = inb + ((long)(y * S - pad) * Winp + (x * S - pad)) * CINP;
    }
    const _Float16* wbc = wB + (size_t)(co0 + wc * 32 + lr) * 8;

    f4 acc[MT][2];
#pragma unroll
    for (int i = 0; i < MT; ++i)
#pragma unroll
        for (int j = 0; j < 2; ++j) { f4 z = {0.f, 0.f, 0.f, 0.f}; acc[i][j] = z; }

    const int Ksteps = Kpad >> 5;

    auto load_step = [&](int kb, h8* afX, h8* bfX) {
        int k0 = kb * 32 + lq * 8;
        int tap = k0 / CINP;              // CINP mult of 8 -> no straddle
        int ci0 = k0 - tap * CINP;
        int dy = tap / KW, dx = tap - dy * KW;
        size_t kq = (size_t)(kb * 4 + lq) * Coutp;
#pragma unroll
        for (int nt = 0; nt < 2; ++nt)
            bfX[nt] = *(const h8*)(wbc + (kq + nt * 16) * 8);
        int doff = (dy * Winp + dx) * CINP + ci0;
#pragma unroll
        for (int mt = 0; mt < MT; ++mt)
            afX[mt] = *(const h8*)(pb[mt] + doff);
    };
    auto mfma_step = [&](h8* afX, h8* bfX) {
#pragma unroll
        for (int mt = 0; mt < MT; ++mt)
#pragma unroll
            for (int nt = 0; nt < 2; ++nt)
                acc[mt][nt] = __builtin_amdgcn_mfma_f32_16x16x32_f16(
                    afX[mt], bfX[nt], acc[mt][nt], 0, 0, 0);
    };

    h8 afA[MT], bfA[2], afB[MT], bfB[2];
    load_step(0, afA, bfA);
    int kb = 0;
    for (; kb + 1 < Ksteps; kb += 2) {
        load_step(kb + 1, afB, bfB);
        mfma_step(afA, bfA);
        if (kb + 2 < Ksteps) load_step(kb + 2, afA, bfA);
        mfma_step(afB, bfB);
    }
    if (kb < Ksteps) mfma_step(afA, bfA);

    _Float16* ob = outI + (size_t)n_img * outStride;
#pragma unroll
    for (int nt = 0; nt < 2; ++nt) {
        int co = co0 + wc * 32 + nt * 16 + lr;
        if (co >= storeC) continue;
        bool valid = co < Cout;
        float bv = (bias && valid) ? bias[co] : 0.f;
#pragma unroll
        for (int mt = 0; mt < MT; ++mt) {
#pragma unroll
            for (int reg = 0; reg < 4; ++reg) {
                int m = m0 + (wr * MT + mt) * 16 + lq * 4 + reg;
                int y = m / Wout, x = m - y * Wout;
                float v = valid
                    ? fmaxf(fmaf(acc[mt][nt][reg], dsc, bv), 0.f) * osc : 0.f;
                ob[((long)y * Wop + x) * storeC + co] = (_Float16)v;
            }
        }
    }
}

// ---------------------------------------------------------------------------
// Patch crop + half-pixel bilinear (reads haloed NHWC f16 interiors)
// ---------------------------------------------------------------------------
__global__ __launch_bounds__(256) void k_praw(const _Float16* __restrict__ f3hI,
    const _Float16* __restrict__ f4hI, const int* __restrict__ meta,
    float* __restrict__ praw)
{
    int z = blockIdx.z;
    int p = z % 3, m = z / 3, lvl = m % 2, b = m / 2;
    int c = blockIdx.y;
    int FC = lvl ? 1024 : 512;
    if (c >= FC) return;
    int FHp = lvl ? 48 : 72;
    int fsh = lvl ? 10 : 9;
    const int* mb = meta + m * 32;
    int PH = mb[12], PW = mb[13];
    int oy = threadIdx.x / 16, ox = threadIdx.x % 16;
    if (oy >= PH || ox >= PW) return;
    int top = mb[p * 4 + 0], left = mb[p * 4 + 1];
    int bot = mb[p * 4 + 2], rgt = mb[p * 4 + 3];
    int h = bot - top, w = rgt - left;
    const _Float16* fm = lvl ? (f4hI + (size_t)b * 2359296)
                             : (f3hI + (size_t)b * 2654208);
    float sy = ((oy + 0.5f) * h) / PH - 0.5f;
    sy = fminf(fmaxf(sy, 0.f), (float)(h - 1));
    int y0 = (int)floorf(sy); float ty = sy - y0; int y1 = min(y0 + 1, h - 1);
    float sx = ((ox + 0.5f) * w) / PW - 0.5f;
    sx = fminf(fmaxf(sx, 0.f), (float)(w - 1));
    int x0 = (int)floorf(sx); float tx = sx - x0; int x1 = min(x0 + 1, w - 1);
    float v00 = (float)fm[((size_t)((top + y0) * FHp + (left + x0)) << fsh) + c];
    float v01 = (float)fm[((size_t)((top + y0) * FHp + (left + x1)) << fsh) + c];
    float v10 = (float)fm[((size_t)((top + y1) * FHp + (left + x0)) << fsh) + c];
    float v11 = (float)fm[((size_t)((top + y1) * FHp + (left + x1)) << fsh) + c];
    float v = (1.f - ty) * ((1.f - tx) * v00 + tx * v01)
            +        ty  * ((1.f - tx) * v10 + tx * v11);
    size_t base = (size_t)(b * 1179648 + (lvl ? 393216 : 0)) + ((size_t)p * FC + c) * 256;
    praw[base + oy * 16 + ox] = v;
}

// ---------------------------------------------------------------------------
__global__ __launch_bounds__(256) void k_psc(const float* __restrict__ praw,
    const int* __restrict__ meta, float* __restrict__ psc)
{
    int z = blockIdx.z;
    int p = z % 3, s = (z / 3) % 3, lvl = (z / 9) % 2, b = z / 18;
    int c = blockIdx.y;
    int FC = lvl ? 1024 : 512;
    if (c >= FC) return;
    const int* mb = meta + (b * 2 + lvl) * 32;
    int PH = mb[12], PW = mb[13];
    int PHs = mb[14 + s * 2], PWs = mb[15 + s * 2];
    int idx = blockIdx.x * 256 + threadIdx.x;
    int ys = idx / 18, xs = idx % 18;
    if (ys >= PHs || xs >= PWs) return;
    const float* src = praw + (size_t)(b * 1179648 + (lvl ? 393216 : 0))
                            + ((size_t)p * FC + c) * 256;
    float sy = ((ys + 0.5f) * PH) / PHs - 0.5f;
    sy = fminf(fmaxf(sy, 0.f), (float)(PH - 1));
    int y0 = (int)floorf(sy); float ty = sy - y0; int y1 = min(y0 + 1, PH - 1);
    float sx = ((xs + 0.5f) * PW) / PWs - 0.5f;
    sx = fminf(fmaxf(sx, 0.f), (float)(PW - 1));
    int x0 = (int)floorf(sx); float tx = sx - x0; int x1 = min(x0 + 1, PW - 1);
    float v = (1.f - ty) * ((1.f - tx) * src[y0 * 16 + x0] + tx * src[y0 * 16 + x1])
            +        ty  * ((1.f - tx) * src[y1 * 16 + x0] + tx * src[y1 * 16 + x1]);
    size_t base = (size_t)b * 4478976 + (lvl ? (1492992 + (size_t)s * 995328)
                                             : ((size_t)s * 497664));
    psc[base + ((size_t)p * FC + c) * 324 + ys * 18 + xs] = v;
}

__global__ __launch_bounds__(256) void k_fill0(float* p, int n)
{
    int i = blockIdx.x * 256 + threadIdx.x;
    if (i < n) p[i] = 0.f;
}

// ---------------------------------------------------------------------------
// Sim filter bank, k = tap*FC + c ordering: Wz[kq][n(16)][8] f16.
// ---------------------------------------------------------------------------
__global__ __launch_bounds__(256) void k_wsim(const float* __restrict__ psc,
    const int* __restrict__ meta, _Float16* __restrict__ W)
{
    int z = blockIdx.z;                 // b*2+lvl
    int lvl = z & 1, b = z >> 1;
    int FC = lvl ? 1024 : 512;
    int fsh = lvl ? 10 : 9;
    int total = FC * 324 * 16;
    int e = blockIdx.x * 256 + threadIdx.x;
    if (e >= total) return;
    _Float16* Wz = W + (size_t)b * 7962624 + (lvl ? 2654208 : 0);
    int j = e & 7, n = (e >> 3) & 15, kq = e >> 7;
    int k = kq * 8 + j;
    int tap = k >> fsh, c = k & (FC - 1);
    int rr = tap / 18, cc = tap - rr * 18;
    float v = 0.f;
    if (n < 9) {
        int s = n / 3, p = n % 3;
        const int* mb = meta + z * 32;
        int PHs = mb[14 + s * 2], PWs = mb[15 + s * 2];
        int ky = rr - (9 - (PHs >> 1));
        int kx = cc - (9 - (PWs >> 1));
        if ((unsigned)ky < (unsigned)PHs && (unsigned)kx < (unsigned)PWs) {
            size_t base = (size_t)b * 4478976 + (lvl ? (1492992 + (size_t)s * 995328)
                                                     : ((size_t)s * 497664));
            v = psc[base + ((size_t)p * FC + c) * 324 + ky * 18 + kx];
        }
    }
    Wz[e] = (_Float16)v;
}

// ---------------------------------------------------------------------------
// Sim GEMM, halo NHWC, no bounds checks, software-pipelined.
// Grid (mg, kchunk, b); wave owns TW 16-px m-subtiles. Split-K atomicAdd.
// ---------------------------------------------------------------------------
template<int TW, int FH, int FHP, int FSH, bool LVL>
__global__ __launch_bounds__(256) void k_simL(
    const _Float16* __restrict__ fI, long fStride,
    const _Float16* __restrict__ W, float* __restrict__ simraw, int Kc)
{
    const int M = FH * FH;
    const int b = blockIdx.z;
    const int mg = blockIdx.x;
    const int kstart = blockIdx.y * Kc;
    const _Float16* fm = fI + (size_t)b * fStride;
    const _Float16* Wz = W + (size_t)b * 7962624;
    const int tid = threadIdx.x;
    const int wv = tid >> 6, lane = tid & 63;
    const int lq = lane >> 4, lr = lane & 15;

    const _Float16* pb[TW];
#pragma unroll
    for (int i = 0; i < TW; ++i) {
        int st = mg * (4 * TW) + wv + 4 * i;
        int m = st * 16 + lr;
        int yb = m / FH - 9, xb = m % FH - 9;
        pb[i] = fm + (((long)yb * FHP + xb) << FSH);
    }
    f4 acc[TW];
#pragma unroll
    for (int i = 0; i < TW; ++i) { f4 z = {0.f, 0.f, 0.f, 0.f}; acc[i] = z; }

    auto load_step = [&](int ks, h8* avX, h8& bfX) {
        int k0 = ks * 32;
        int tap = k0 >> FSH;                       // uniform (scalar)
        int c0 = (k0 & ((1 << FSH) - 1)) + lq * 8;
        int dy = tap / 18, dx = tap - dy * 18;
        bfX = *(const h8*)(Wz + ((size_t)((k0 >> 3) + lq) * 16 + lr) * 8);
        long doff = ((long)(dy * FHP + dx) << FSH) + c0;
#pragma unroll
        for (int i = 0; i < TW; ++i)
            avX[i] = *(const h8*)(pb[i] + doff);
    };
    auto mfma_step = [&](h8* avX, h8 bfX) {
#pragma unroll
        for (int i = 0; i < TW; ++i)
            acc[i] = __builtin_amdgcn_mfma_f32_16x16x32_f16(avX[i], bfX, acc[i], 0, 0, 0);
    };

    h8 avA[TW], avB[TW], bfA, bfB;
    load_step(kstart, avA, bfA);
    int kb = 0;
    for (; kb + 1 < Kc; kb += 2) {
        load_step(kstart + kb + 1, avB, bfB);
        mfma_step(avA, bfA);
        if (kb + 2 < Kc) load_step(kstart + kb + 2, avA, bfA);
        mfma_step(avB, bfB);
    }
    if (kb < Kc) mfma_step(avA, bfA);

    if (lr < 9) {
        int s = lr / 3, p = lr - s * 3;
        float* base = simraw + (size_t)b * 25920
                    + (LVL ? (20736 + (size_t)s * 1728) : ((size_t)s * 6912))
                    + (size_t)p * M;
#pragma unroll
        for (int i = 0; i < TW; ++i) {
            int st = mg * (4 * TW) + wv + 4 * i;
            int row0 = st * 16 + lq * 4;
#pragma unroll
            for (int r = 0; r < 4; ++r) {
                int m = row0 + r;
                if (m < M) atomicAdd(base + m, acc[i][r]);
            }
        }
    }
}

// ---------------------------------------------------------------------------
// Assemble sims -> haloed NHWC f16 interior, stored x 2^-10 (r1 dsc=1024)
// ---------------------------------------------------------------------------
__global__ __launch_bounds__(256) void k_sims(const float* __restrict__ simraw,
    _Float16* __restrict__ simshI)
{
    int idx = blockIdx.x * 256 + threadIdx.x;
    if (idx >= 110592) return;
    int scat = idx & 7;
    int rest = idx >> 3;
    int x = rest % 48, y = (rest / 48) % 48;
    int p = (rest / 2304) % 3, b = rest / 6912;
    float v = 0.f;
    if (scat < 6) {
        int lvl = scat / 3, s = scat % 3;
        if (lvl == 0) {
            v = simraw[(size_t)b * 25920 + (size_t)s * 6912 + (size_t)p * 2304 + y * 48 + x];
        } else {
            const float* src = simraw + (size_t)b * 25920 + 20736 + (size_t)s * 1728
                                      + (size_t)p * 576;
            float sy = (y + 0.5f) * 0.5f - 0.5f; sy = fminf(fmaxf(sy, 0.f), 23.f);
            int y0 = (int)floorf(sy); float ty = sy - y0; int y1 = min(y0 + 1, 23);
            float sx = (x + 0.5f) * 0.5f - 0.5f; sx = fminf(fmaxf(sx, 0.f), 23.f);
            int x0 = (int)floorf(sx); float tx = sx - x0; int x1 = min(x0 + 1, 23);
            v = (1.f - ty) * ((1.f - tx) * src[y0 * 24 + x0] + tx * src[y0 * 24 + x1])
              +        ty  * ((1.f - tx) * src[y1 * 24 + x0] + tx * src[y1 * 24 + x1]);
        }
    }
    int n = b * 3 + p;
    simshI[((size_t)n * 32768 + ((size_t)y * 64 + x) * 8) + scat]
        = (_Float16)(v * 0.0009765625f);   // x 2^-10
}

// ---------------------------------------------------------------------------
// align-corners 2x bilinear upsample, NHWC f16 (h8 vectors), strided in/out
// ---------------------------------------------------------------------------
__global__ __launch_bounds__(256) void k_up2acH(const h8* __restrict__ inI,
    int inWp, long inStride, h8* __restrict__ outI, int outWp, long outStride,
    int N_, int Hin, int Win, int Cg)
{
    int Hout = 2 * Hin, Wout = 2 * Win;
    size_t total = (size_t)N_ * Hout * Wout * Cg;
    size_t idx = (size_t)blockIdx.x * 256 + threadIdx.x;
    if (idx >= total) return;
    int cg = (int)(idx % Cg);
    size_t r = idx / Cg;
    int x = (int)(r % Wout);
    int y = (int)((r / Wout) % Hout);
    int n = (int)(r / ((size_t)Wout * Hout));
    int dh = 2 * Hin - 1, dw = 2 * Win - 1;
    int ay = y * (Hin - 1);
    int y0 = ay / dh; int y1 = min(y0 + 1, Hin - 1);
    float ty = (float)(ay - y0 * dh) / (float)dh;
    int ax = x * (Win - 1);
    int x0 = ax / dw; int x1 = min(x0 + 1, Win - 1);
    float tx = (float)(ax - x0 * dw) / (float)dw;
    const h8* base = inI + (size_t)n * inStride;
    h8 a = base[((size_t)y0 * inWp + x0) * Cg + cg];
    h8 b8 = base[((size_t)y0 * inWp + x1) * Cg + cg];
    h8 c8 = base[((size_t)y1 * inWp + x0) * Cg + cg];
    h8 d8 = base[((size_t)y1 * inWp + x1) * Cg + cg];
    float w00 = (1.f - ty) * (1.f - tx), w01 = (1.f - ty) * tx;
    float w10 = ty * (1.f - tx), w11 = ty * tx;
    h8 o;
#pragma unroll
    for (int j = 0; j < 8; ++j)
        o[j] = (_Float16)(w00 * (float)a[j] + w01 * (float)b8[j]
                        + w10 * (float)c8[j] + w11 * (float)d8[j]);
    outI[(size_t)n * outStride + ((size_t)y * outWp + x) * Cg + cg] = o;
}

// ---------------------------------------------------------------------------
__global__ __launch_bounds__(256) void k_final(const h8* __restrict__ r3h,
    const float* __restrict__ w4, const float* __restrict__ b4,
    const float* __restrict__ w5, const float* __restrict__ b5,
    float* __restrict__ out)
{
    __shared__ float sw4[2048];
    __shared__ float sb4[32];
    __shared__ float sw5[32];
    int tid = threadIdx.x;
    for (int i = tid; i < 2048; i += 256) sw4[i] = w4[i];
    if (tid < 32) { sb4[tid] = b4[tid]; sw5[tid] = w5[tid]; }
    __syncthreads();
    int idx = blockIdx.x * 256 + tid;
    int x = idx % 384, y = (idx / 384) % 384, b = idx / 147456;
    int ay = y * 191; int y0 = ay / 383; int y1 = min(y0 + 1, 191);
    float ty = (float)(ay - y0 * 383) / 383.f;
    int ax = x * 191; int x0 = ax / 383; int x1 = min(x0 + 1, 191);
    float tx = (float)(ax - x0 * 383) / 383.f;
    float w00 = (1.f - ty) * (1.f - tx), w01 = (1.f - ty) * tx;
    float w10 = ty * (1.f - tx), w11 = ty * tx;
    float best = 0.f;
    for (int p = 0; p < 3; ++p) {
        int n = b * 3 + p;
        float acc[32];
#pragma unroll
        for (int co = 0; co < 32; ++co) acc[co] = sb4[co];
        const h8* rb = r3h + (size_t)n * 36864 * 8;
        for (int cg = 0; cg < 8; ++cg) {
            h8 a00 = rb[(size_t)(y0 * 192 + x0) * 8 + cg];
            h8 a01 = rb[(size_t)(y0 * 192 + x1) * 8 + cg];
            h8 a10 = rb[(size_t)(y1 * 192 + x0) * 8 + cg];
            h8 a11 = rb[(size_t)(y1 * 192 + x1) * 8 + cg];
#pragma unroll
            for (int jj = 0; jj < 8; ++jj) {
                float v = (w00 * (float)a00[jj] + w01 * (float)a01[jj]
                         + w10 * (float)a10[jj] + w11 * (float)a11[jj]) * 64.f;
                int ci = cg * 8 + jj;
#pragma unroll
                for (int co = 0; co < 32; ++co)
                    acc[co] = fmaf(sw4[co * 64 + ci], v, acc[co]);
            }
        }
        float s5 = b5[0];
#pragma unroll
        for (int co = 0; co < 32; ++co)
            s5 = fmaf(fmaxf(acc[co], 0.f), sw5[co], s5);
        s5 = fmaxf(s5, 0.f);
        best = fmaxf(best, s5);
    }
    out[idx] = best;
}

// ---------------------------------------------------------------------------
extern "C" void kernel_launch(void* const* d_in, const int* in_sizes, int n_in,
                              void* d_out, int out_size, void* d_ws, size_t ws_size,
                              hipStream_t stream)
{
    (void)in_sizes; (void)n_in; (void)out_size; (void)ws_size;
    const float* images = (const float*)d_in[0];
    const float* tlbrs  = (const float*)d_in[1];
    const float* fw1 = (const float*)d_in[2];
    const float* fw2 = (const float*)d_in[3];
    const float* fw3 = (const float*)d_in[4];
    const float* fw4 = (const float*)d_in[5];
    const float* rw1 = (const float*)d_in[6];
    const float* rb1 = (const float*)d_in[7];
    const float* rw2 = (const float*)d_in[8];
    const float* rb2 = (const float*)d_in[9];
    const float* rw3 = (const float*)d_in[10];
    const float* rb3 = (const float*)d_in[11];
    const float* rw4 = (const float*)d_in[12];
    const float* rb4 = (const float*)d_in[13];
    const float* rw5 = (const float*)d_in[14];
    const float* rb5 = (const float*)d_in[15];
    float* wsf = (float*)d_ws;
    int* meta = (int*)d_ws;
    float* out = (float*)d_out;
    _Float16* wb = (_Float16*)(wsf + OFF_WB);

    // interior pointers (halo offsets)
    _Float16* imhI   = (_Float16*)(wsf + IMH)  + (8 * 400 + 8) * 8;
    _Float16* b1hI   = (_Float16*)(wsf + B1H)  + (8 * 208 + 8) * 64;
    _Float16* b2hI   = (_Float16*)(wsf + B2H)  + (8 * 112 + 8) * 256;
    _Float16* f3hI   = (_Float16*)(wsf + F3H)  + (12 * 72 + 12) * 512;
    _Float16* f4hI   = (_Float16*)(wsf + F4H)  + (12 * 48 + 12) * 1024;
    _Float16* simshI = (_Float16*)(wsf + OFF_SIMSH) + (8 * 64 + 8) * 8;
    _Float16* r1hI   = (_Float16*)(wsf + R1H)  + (8 * 64 + 8) * 200;
    _Float16* u1hI   = (_Float16*)(wsf + U1H)  + (8 * 112 + 8) * 200;
    _Float16* r2h    = (_Float16*)(wsf + R2H);
    _Float16* u2hI   = (_Float16*)(wsf + U2H)  + (8 * 208 + 8) * 128;
    _Float16* r3h    = (_Float16*)(wsf + R3H);
    _Float16* wsim   = (_Float16*)(wsf + WSIM);

    const float INV64 = 1.f / 64.f;

    hipLaunchKernelGGL(k_halos1, dim3(1728, 5), dim3(256), 0, stream, wsf);
    hipLaunchKernelGGL(k_meta, dim3(1), dim3(64), 0, stream, tlbrs, meta);
    hipLaunchKernelGGL(k_im2hwc, dim3(9216), dim3(256), 0, stream, images,
        (_Float16*)(wsf + IMH));

    // ---- weight banks ----
    hipLaunchKernelGGL(k_wprepH, dim3(104), dim3(256), 0, stream,
        fw1, wb + WB1, 3, 49, 8, 64, 64, 26624);
    hipLaunchKernelGGL(k_wprepH, dim3(576), dim3(256), 0, stream,
        fw2, wb + WB2, 64, 9, 64, 256, 256, 147456);
    hipLaunchKernelGGL(k_wprepH, dim3(4608), dim3(256), 0, stream,
        fw3, wb + WB3, 256, 9, 256, 512, 512, 1179648);
    hipLaunchKernelGGL(k_wprepH, dim3(18432), dim3(256), 0, stream,
        fw4, wb + WB4, 512, 9, 512, 1024, 1024, 4718592);
    hipLaunchKernelGGL(k_wprepH, dim3(416), dim3(256), 0, stream,
        rw1, wb + WR1, 6, 49, 8, 196, 256, 106496);
    hipLaunchKernelGGL(k_wprepH, dim3(2512), dim3(256), 0, stream,
        rw2, wb + WR2, 196, 25, 200, 128, 128, 643072);
    hipLaunchKernelGGL(k_wprepH, dim3(288), dim3(256), 0, stream,
        rw3, wb + WR3, 128, 9, 128, 64, 64, 73728);

    // ---- backbone ----
    hipLaunchKernelGGL((k_convH<49, 7, 2, 8, 2>), dim3(576, 1, 2), dim3(256), 0, stream,
        imhI, 400, 1280000L, wb + WB1, (const float*)nullptr,
        b1hI, 208, 2768896L, 64, 64, 192, 3, 416, 64, 1.f, 1.f);
    hipLaunchKernelGGL((k_convH<9, 3, 2, 64, 2>), dim3(144, 4, 2), dim3(256), 0, stream,
        b1hI, 208, 2768896L, wb + WB2, (const float*)nullptr,
        b2hI, 112, 3211264L, 256, 256, 96, 1, 576, 256, 1.f, 1.f);
    hipLaunchKernelGGL((k_convH<9, 3, 2, 256, 2>), dim3(36, 8, 2), dim3(256), 0, stream,
        b2hI, 112, 3211264L, wb + WB3, (const float*)nullptr,
        f3hI, 72, 2654208L, 512, 512, 48, 1, 2304, 512, 1.f, 1.f);
    hipLaunchKernelGGL((k_convH<9, 3, 2, 512, 2>), dim3(9, 16, 2), dim3(256), 0, stream,
        f3hI, 72, 2654208L, wb + WB4, (const float*)nullptr,
        f4hI, 48, 2359296L, 1024, 1024, 24, 1, 4608, 1024, 1.f, 1.f);

    // ---- feature extraction ----
    hipLaunchKernelGGL(k_praw, dim3(1, 1024, 12), dim3(256), 0, stream,
        f3hI, f4hI, meta, wsf + PRAW);
    hipLaunchKernelGGL(k_psc, dim3(2, 1024, 36), dim3(256), 0, stream,
        wsf + PRAW, meta, wsf + PSC);
    hipLaunchKernelGGL(k_wsim, dim3(20736, 1, 4), dim3(256), 0, stream,
        wsf + PSC, meta, wsim);
    hipLaunchKernelGGL(k_fill0, dim3(203), dim3(256), 0, stream,
        wsf + SIMRAW, 51840);
    hipLaunchKernelGGL((k_simL<6, 48, 72, 9, false>), dim3(6, 96, 2), dim3(256), 0, stream,
        f3hI, 2654208L, wsim, wsf + SIMRAW, 54);
    hipLaunchKernelGGL((k_simL<3, 24, 48, 10, true>), dim3(3, 144, 2), dim3(256), 0, stream,
        f4hI, 2359296L, wsim + 2654208, wsf + SIMRAW, 72);
    hipLaunchKernelGGL(k_sims, dim3(432), dim3(256), 0, stream,
        wsf + SIMRAW, simshI);
    // phase-2 halos (f3h/f4h/PSC/WSIM dead from here)
    hipLaunchKernelGGL(k_halos2, dim3(2400, 4), dim3(256), 0, stream, wsf);

    // ---- count regressor ----
    hipLaunchKernelGGL((k_convH<49, 7, 1, 8, 2>), dim3(36, 4, 6), dim3(256), 0, stream,
        simshI, 64, 32768L, wb + WR1, rb1,
        r1hI, 64, 819200L, 196, 256, 48, 3, 416, 200, 1024.f, INV64);
    hipLaunchKernelGGL(k_up2acH, dim3(5400), dim3(256), 0, stream,
        (const h8*)r1hI, 64, 102400L, (h8*)u1hI, 112, 313600L, 6, 48, 48, 25);
    hipLaunchKernelGGL((k_convH<25, 5, 1, 200, 2>), dim3(144, 2, 6), dim3(256), 0, stream,
        u1hI, 112, 2508800L, wb + WR2, rb2,
        r2h, 96, 1179648L, 128, 128, 96, 2, 5024, 128, 64.f, INV64);
    hipLaunchKernelGGL(k_up2acH, dim3(13824), dim3(256), 0, stream,
        (const h8*)r2h, 96, 147456L, (h8*)u2hI, 208, 692224L, 6, 96, 96, 16);
    hipLaunchKernelGGL((k_convH<9, 3, 1, 128, 4>), dim3(288, 1, 6), dim3(256), 0, stream,
        u2hI, 208, 5537792L, wb + WR3, rb3,
        r3h, 192, 2359296L, 64, 64, 192, 1, 1152, 64, 64.f, INV64);
    hipLaunchKernelGGL(k_final, dim3(1152), dim3(256), 0, stream,
        (const h8*)r3h, rw4, rb4, rw5, rb5, out);
}

// Round 13
// 1216.408 us; speedup vs baseline: 1.0922x; 1.0922x over previous
//
#include <hip/hip_runtime.h>
#include <math.h>

typedef _Float16 h8 __attribute__((ext_vector_type(8)));
typedef float f4 __attribute__((ext_vector_type(4)));

// ---------------------------------------------------------------------------
// Workspace layout (float units). All activations NHWC f16 with spatial HALO
// (zero-filled) so conv/sim gathers need no bounds checks. Peak ~163 MB.
// Scale chain: sims stored x2^-10, r1 dsc=1024; regressor acts x1/64,
// consumers dsc=64; k_final x64. All pow2 (exact).
// ---------------------------------------------------------------------------
static const size_t OFF_SIMSH = 256;       // (6, 64x64, 8) h halo8 = 98304 fl
static const size_t OFF_WB    = 98560;     // weight banks, 6895616 h
static const size_t ARENA     = 3546368;
// phase 1
static const size_t IMH  = 3546368;    // (2,400x400,8) h halo8
static const size_t B1H  = 4826368;    // (2,208x208,64) halo8
static const size_t B2H  = 7595264;    // (2,112x112,256) halo8
static const size_t F3H  = 10806528;   // (2,72x72,512) halo12
static const size_t F4H  = 13460736;   // (2,48x48,1024) halo12
static const size_t PRAW = 15820032;   // fp32 2359296
static const size_t PSC  = 18179328;   // fp32 8957952
static const size_t SIMRAW = 27137280; // fp32 51840
static const size_t WSIM = 27189120;   // f16 15925248 h -> end 35151744
// phase 2 (reuses arena after k_sims)
static const size_t R1H = 3546368;     // (6,64x64,200) halo8
static const size_t U1H = 6003968;     // (6,112x112,200) halo8
static const size_t R2H = 13530368;    // (6,96x96,128) no halo
static const size_t U2H = 17069312;    // (6,208x208,128) halo8
static const size_t R3H = 33676544;    // (6,192x192,64) no halo -> end 40754432

// f16-unit offsets inside WB bank
static const size_t WB1 = 0;          // 52kq x 64
static const size_t WB2 = 26624;      // 72 x 256
static const size_t WB3 = 174080;     // 288 x 512
static const size_t WB4 = 1353728;    // 576 x 1024
static const size_t WR1 = 6072320;    // 52 x 256
static const size_t WR2 = 6178816;    // 628 x 128
static const size_t WR3 = 6821888;    // 144 x 64

// ---------------------------------------------------------------------------
__global__ __launch_bounds__(64) void k_meta(const float* __restrict__ tlbrs,
                                             int* __restrict__ meta)
{
    if (threadIdx.x != 0 || blockIdx.x != 0) return;
    const double SC[3] = {1.0, 0.9, 1.1};
    for (int b = 0; b < 2; ++b)
        for (int lvl = 0; lvl < 2; ++lvl) {
            int FH = lvl ? 24 : 48;
            float scaling = lvl ? 16.f : 8.f;
            int base = (b * 2 + lvl) * 32;
            int PH = 0, PW = 0;
            for (int p = 0; p < 3; ++p) {
                const float* t4 = tlbrs + (b * 3 + p) * 4;
                float st = t4[0] / scaling, sl = t4[1] / scaling;
                float sb = t4[2] / scaling, sr = t4[3] / scaling;
                int top  = (int)fmaxf(floorf(st), 0.f);
                int left = (int)fmaxf(floorf(sl), 0.f);
                int bot  = (int)fminf(ceilf(sb) + 1.f, (float)FH);
                int rgt  = (int)fminf(ceilf(sr) + 1.f, (float)FH);
                meta[base + p * 4 + 0] = top;
                meta[base + p * 4 + 1] = left;
                meta[base + p * 4 + 2] = bot;
                meta[base + p * 4 + 3] = rgt;
                PH = max(PH, bot - top);
                PW = max(PW, rgt - left);
            }
            meta[base + 12] = PH;
            meta[base + 13] = PW;
            for (int s = 0; s < 3; ++s) {
                int PHs = (int)ceil((double)PH * SC[s]);
                int PWs = (int)ceil((double)PW * SC[s]);
                if (PHs < 1) PHs = PH;
                if (PWs < 1) PWs = PW;
                meta[base + 14 + s * 2] = PHs;
                meta[base + 15 + s * 2] = PWs;
            }
        }
}

// ---------------------------------------------------------------------------
// Zero the halo frames (ws is re-poisoned each launch).
// ---------------------------------------------------------------------------
__device__ __forceinline__ void halo_zero(h8* base, int Hp, int Wp, int halo,
                                          int Cg, int N)
{
    int inner = Hp - 2 * halo;
    int frame = Hp * Wp - inner * inner;
    long total = (long)N * frame * Cg;
    long idx = (long)blockIdx.x * 256 + threadIdx.x;
    if (idx >= total) return;
    int cg = (int)(idx % Cg);
    long r = idx / Cg;
    int f = (int)(r % frame);
    int n = (int)(r / frame);
    int topN = halo * Wp;
    int y, x;
    if (f < topN) { y = f / Wp; x = f % Wp; }
    else if (f < 2 * topN) { int f2 = f - topN; y = Hp - halo + f2 / Wp; x = f2 % Wp; }
    else {
        int f3 = f - 2 * topN;
        int row = f3 / (2 * halo), rr = f3 - row * (2 * halo);
        y = halo + row;
        x = rr < halo ? rr : Wp - 2 * halo + rr;
    }
    h8 z;
#pragma unroll
    for (int j = 0; j < 8; ++j) z[j] = (_Float16)0.f;
    base[((long)n * Hp * Wp + (long)y * Wp + x) * Cg + cg] = z;
}

__global__ __launch_bounds__(256) void k_halos1(float* wsf)
{
    switch (blockIdx.y) {
    case 0: halo_zero((h8*)(wsf + IMH), 400, 400, 8, 1, 2); break;
    case 1: halo_zero((h8*)(wsf + B1H), 208, 208, 8, 8, 2); break;
    case 2: halo_zero((h8*)(wsf + B2H), 112, 112, 8, 32, 2); break;
    case 3: halo_zero((h8*)(wsf + F3H), 72, 72, 12, 64, 2); break;
    default: halo_zero((h8*)(wsf + F4H), 48, 48, 12, 128, 2); break;
    }
}

__global__ __launch_bounds__(256) void k_halos2(float* wsf)
{
    switch (blockIdx.y) {
    case 0: halo_zero((h8*)(wsf + OFF_SIMSH), 64, 64, 8, 1, 6); break;
    case 1: halo_zero((h8*)(wsf + R1H), 64, 64, 8, 25, 6); break;
    case 2: halo_zero((h8*)(wsf + U1H), 112, 112, 8, 25, 6); break;
    default: halo_zero((h8*)(wsf + U2H), 208, 208, 8, 16, 6); break;
    }
}

// ---------------------------------------------------------------------------
// images NCHW fp32 -> NHWC f16 interior of halo-padded (400x400)
// ---------------------------------------------------------------------------
__global__ __launch_bounds__(256) void k_im2hwc(const float* __restrict__ img,
    _Float16* __restrict__ o)
{
    int idx = blockIdx.x * 256 + threadIdx.x;
    if (idx >= 2359296) return;
    int c = idx & 7;
    int pix = (idx >> 3) % 147456;
    int b = (idx >> 3) / 147456;
    int y = pix / 384, x = pix - y * 384;
    float v = (c < 3) ? img[((size_t)b * 3 + c) * 147456 + pix] : 0.f;
    o[((size_t)b * 1280000 + ((size_t)(y + 8) * 400 + (x + 8)) * 8) + c] = (_Float16)v;
}

// ---------------------------------------------------------------------------
__global__ __launch_bounds__(256) void k_wprepH(const float* __restrict__ w,
    _Float16* __restrict__ wB, int Cin, int KKt, int Cinp, int Cout, int Coutp,
    int total)
{
    int idx = blockIdx.x * 256 + threadIdx.x;
    if (idx >= total) return;
    int j = idx & 7;
    int co = (idx >> 3) % Coutp;
    int kq = idx / (8 * Coutp);
    int k = kq * 8 + j;
    int tap = k / Cinp, cip = k - tap * Cinp;
    float v = 0.f;
    if (tap < KKt && cip < Cin && co < Cout)
        v = w[((size_t)co * Cin + cip) * KKt + tap];
    wB[idx] = (_Float16)v;
}

// ---------------------------------------------------------------------------
// Halo NHWC implicit-GEMM conv, NT=4 outer product: each wave owns the full
// 64-co tile and MT m-frags -> MT*4 MFMAs per MT+4 loads (load:MFMA 0.75 at
// MT=2 vs 1.0 before). BM = 64*MT, BN = 64. No bounds checks (halo + zero-
// padded wB). Software-pipelined depth 1, LDS-free, f16 MFMA fp32 accum.
// ---------------------------------------------------------------------------
template<int KK, int KW, int S, int CINP, int MT>
__global__ __launch_bounds__(256) void k_convH(
    const _Float16* __restrict__ inI, int Winp, long inStride,
    const _Float16* __restrict__ wB, const float* __restrict__ bias,
    _Float16* __restrict__ outI, int Wop, long outStride,
    int Cout, int Coutp, int Wout, int pad, int Kpad, int storeC,
    float dsc, float osc)
{
    const int tid = threadIdx.x;
    const int n_img = blockIdx.z;
    const int m0 = blockIdx.x * (MT * 64);
    const int co0 = blockIdx.y * 64;
    const _Float16* inb = inI + (size_t)n_img * inStride;

    const int wv = tid >> 6, lane = tid & 63;
    const int lq = lane >> 4, lr = lane & 15;

    const _Float16* pb[MT];
#pragma unroll
    for (int mt = 0; mt < MT; ++mt) {
        int m = m0 + (wv * MT + mt) * 16 + lr;
        int y = m / Wout, x = m - y * Wout;
        pb[mt] = inb + ((long)(y * S - pad) * Winp + (x * S - pad)) * CINP;
    }
    const _Float16* wbc = wB + (size_t)(co0 + lr) * 8;

    f4 acc[MT][4];
#pragma unroll
    for (int i = 0; i < MT; ++i)
#pragma unroll
        for (int j = 0; j < 4; ++j) { f4 z = {0.f, 0.f, 0.f, 0.f}; acc[i][j] = z; }

    const int Ksteps = Kpad >> 5;

    auto load_step = [&](int kb, h8* afX, h8* bfX) {
        int k0 = kb * 32 + lq * 8;
        int tap = k0 / CINP;              // CINP mult of 8 -> no straddle
        int ci0 = k0 - tap * CINP;
        int dy = tap / KW, dx = tap - dy * KW;
        size_t kq = (size_t)(kb * 4 + lq) * Coutp;
#pragma unroll
        for (int nt = 0; nt < 4; ++nt)
            bfX[nt] = *(const h8*)(wbc + (kq + nt * 16) * 8);
        int doff = (dy * Winp + dx) * CINP + ci0;
#pragma unroll
        for (int mt = 0; mt < MT; ++mt)
            afX[mt] = *(const h8*)(pb[mt] + doff);
    };
    auto mfma_step = [&](h8* afX, h8* bfX) {
#pragma unroll
        for (int mt = 0; mt < MT; ++mt)
#pragma unroll
            for (int nt = 0; nt < 4; ++nt)
                acc[mt][nt] = __builtin_amdgcn_mfma_f32_16x16x32_f16(
                    afX[mt], bfX[nt], acc[mt][nt], 0, 0, 0);
    };

    h8 afA[MT], bfA[4], afB[MT], bfB[4];
    load_step(0, afA, bfA);
    int kb = 0;
    for (; kb + 1 < Ksteps; kb += 2) {
        load_step(kb + 1, afB, bfB);
        mfma_step(afA, bfA);
        if (kb + 2 < Ksteps) load_step(kb + 2, afA, bfA);
        mfma_step(afB, bfB);
    }
    if (kb < Ksteps) mfma_step(afA, bfA);

    _Float16* ob = outI + (size_t)n_img * outStride;
#pragma unroll
    for (int nt = 0; nt < 4; ++nt) {
        int co = co0 + nt * 16 + lr;
        if (co >= storeC) continue;
        bool valid = co < Cout;
        float bv = (bias && valid) ? bias[co] : 0.f;
#pragma unroll
        for (int mt = 0; mt < MT; ++mt) {
#pragma unroll
            for (int reg = 0; reg < 4; ++reg) {
                int m = m0 + (wv * MT + mt) * 16 + lq * 4 + reg;
                int y = m / Wout, x = m - y * Wout;
                float v = valid
                    ? fmaxf(fmaf(acc[mt][nt][reg], dsc, bv), 0.f) * osc : 0.f;
                ob[((long)y * Wop + x) * storeC + co] = (_Float16)v;
            }
        }
    }
}

// ---------------------------------------------------------------------------
// Patch crop + half-pixel bilinear (reads haloed NHWC f16 interiors)
// ---------------------------------------------------------------------------
__global__ __launch_bounds__(256) void k_praw(const _Float16* __restrict__ f3hI,
    const _Float16* __restrict__ f4hI, const int* __restrict__ meta,
    float* __restrict__ praw)
{
    int z = blockIdx.z;
    int p = z % 3, m = z / 3, lvl = m % 2, b = m / 2;
    int c = blockIdx.y;
    int FC = lvl ? 1024 : 512;
    if (c >= FC) return;
    int FHp = lvl ? 48 : 72;
    int fsh = lvl ? 10 : 9;
    const int* mb = meta + m * 32;
    int PH = mb[12], PW = mb[13];
    int oy = threadIdx.x / 16, ox = threadIdx.x % 16;
    if (oy >= PH || ox >= PW) return;
    int top = mb[p * 4 + 0], left = mb[p * 4 + 1];
    int bot = mb[p * 4 + 2], rgt = mb[p * 4 + 3];
    int h = bot - top, w = rgt - left;
    const _Float16* fm = lvl ? (f4hI + (size_t)b * 2359296)
                             : (f3hI + (size_t)b * 2654208);
    float sy = ((oy + 0.5f) * h) / PH - 0.5f;
    sy = fminf(fmaxf(sy, 0.f), (float)(h - 1));
    int y0 = (int)floorf(sy); float ty = sy - y0; int y1 = min(y0 + 1, h - 1);
    float sx = ((ox + 0.5f) * w) / PW - 0.5f;
    sx = fminf(fmaxf(sx, 0.f), (float)(w - 1));
    int x0 = (int)floorf(sx); float tx = sx - x0; int x1 = min(x0 + 1, w - 1);
    float v00 = (float)fm[((size_t)((top + y0) * FHp + (left + x0)) << fsh) + c];
    float v01 = (float)fm[((size_t)((top + y0) * FHp + (left + x1)) << fsh) + c];
    float v10 = (float)fm[((size_t)((top + y1) * FHp + (left + x0)) << fsh) + c];
    float v11 = (float)fm[((size_t)((top + y1) * FHp + (left + x1)) << fsh) + c];
    float v = (1.f - ty) * ((1.f - tx) * v00 + tx * v01)
            +        ty  * ((1.f - tx) * v10 + tx * v11);
    size_t base = (size_t)(b * 1179648 + (lvl ? 393216 : 0)) + ((size_t)p * FC + c) * 256;
    praw[base + oy * 16 + ox] = v;
}

// ---------------------------------------------------------------------------
__global__ __launch_bounds__(256) void k_psc(const float* __restrict__ praw,
    const int* __restrict__ meta, float* __restrict__ psc)
{
    int z = blockIdx.z;
    int p = z % 3, s = (z / 3) % 3, lvl = (z / 9) % 2, b = z / 18;
    int c = blockIdx.y;
    int FC = lvl ? 1024 : 512;
    if (c >= FC) return;
    const int* mb = meta + (b * 2 + lvl) * 32;
    int PH = mb[12], PW = mb[13];
    int PHs = mb[14 + s * 2], PWs = mb[15 + s * 2];
    int idx = blockIdx.x * 256 + threadIdx.x;
    int ys = idx / 18, xs = idx % 18;
    if (ys >= PHs || xs >= PWs) return;
    const float* src = praw + (size_t)(b * 1179648 + (lvl ? 393216 : 0))
                            + ((size_t)p * FC + c) * 256;
    float sy = ((ys + 0.5f) * PH) / PHs - 0.5f;
    sy = fminf(fmaxf(sy, 0.f), (float)(PH - 1));
    int y0 = (int)floorf(sy); float ty = sy - y0; int y1 = min(y0 + 1, PH - 1);
    float sx = ((xs + 0.5f) * PW) / PWs - 0.5f;
    sx = fminf(fmaxf(sx, 0.f), (float)(PW - 1));
    int x0 = (int)floorf(sx); float tx = sx - x0; int x1 = min(x0 + 1, PW - 1);
    float v = (1.f - ty) * ((1.f - tx) * src[y0 * 16 + x0] + tx * src[y0 * 16 + x1])
            +        ty  * ((1.f - tx) * src[y1 * 16 + x0] + tx * src[y1 * 16 + x1]);
    size_t base = (size_t)b * 4478976 + (lvl ? (1492992 + (size_t)s * 995328)
                                             : ((size_t)s * 497664));
    psc[base + ((size_t)p * FC + c) * 324 + ys * 18 + xs] = v;
}

__global__ __launch_bounds__(256) void k_fill0(float* p, int n)
{
    int i = blockIdx.x * 256 + threadIdx.x;
    if (i < n) p[i] = 0.f;
}

// ---------------------------------------------------------------------------
// Sim filter bank, k = tap*FC + c ordering: Wz[kq][n(16)][8] f16.
// ---------------------------------------------------------------------------
__global__ __launch_bounds__(256) void k_wsim(const float* __restrict__ psc,
    const int* __restrict__ meta, _Float16* __restrict__ W)
{
    int z = blockIdx.z;                 // b*2+lvl
    int lvl = z & 1, b = z >> 1;
    int FC = lvl ? 1024 : 512;
    int fsh = lvl ? 10 : 9;
    int total = FC * 324 * 16;
    int e = blockIdx.x * 256 + threadIdx.x;
    if (e >= total) return;
    _Float16* Wz = W + (size_t)b * 7962624 + (lvl ? 2654208 : 0);
    int j = e & 7, n = (e >> 3) & 15, kq = e >> 7;
    int k = kq * 8 + j;
    int tap = k >> fsh, c = k & (FC - 1);
    int rr = tap / 18, cc = tap - rr * 18;
    float v = 0.f;
    if (n < 9) {
        int s = n / 3, p = n % 3;
        const int* mb = meta + z * 32;
        int PHs = mb[14 + s * 2], PWs = mb[15 + s * 2];
        int ky = rr - (9 - (PHs >> 1));
        int kx = cc - (9 - (PWs >> 1));
        if ((unsigned)ky < (unsigned)PHs && (unsigned)kx < (unsigned)PWs) {
            size_t base = (size_t)b * 4478976 + (lvl ? (1492992 + (size_t)s * 995328)
                                                     : ((size_t)s * 497664));
            v = psc[base + ((size_t)p * FC + c) * 324 + ky * 18 + kx];
        }
    }
    Wz[e] = (_Float16)v;
}

// ---------------------------------------------------------------------------
// Sim GEMM, halo NHWC, no bounds checks, software-pipelined.
// Grid (mg, kchunk, b); wave owns TW 16-px m-subtiles. Split-K atomicAdd.
// ---------------------------------------------------------------------------
template<int TW, int FH, int FHP, int FSH, bool LVL>
__global__ __launch_bounds__(256) void k_simL(
    const _Float16* __restrict__ fI, long fStride,
    const _Float16* __restrict__ W, float* __restrict__ simraw, int Kc)
{
    const int M = FH * FH;
    const int b = blockIdx.z;
    const int mg = blockIdx.x;
    const int kstart = blockIdx.y * Kc;
    const _Float16* fm = fI + (size_t)b * fStride;
    const _Float16* Wz = W + (size_t)b * 7962624;
    const int tid = threadIdx.x;
    const int wv = tid >> 6, lane = tid & 63;
    const int lq = lane >> 4, lr = lane & 15;

    const _Float16* pb[TW];
#pragma unroll
    for (int i = 0; i < TW; ++i) {
        int st = mg * (4 * TW) + wv + 4 * i;
        int m = st * 16 + lr;
        int yb = m / FH - 9, xb = m % FH - 9;
        pb[i] = fm + (((long)yb * FHP + xb) << FSH);
    }
    f4 acc[TW];
#pragma unroll
    for (int i = 0; i < TW; ++i) { f4 z = {0.f, 0.f, 0.f, 0.f}; acc[i] = z; }

    auto load_step = [&](int ks, h8* avX, h8& bfX) {
        int k0 = ks * 32;
        int tap = k0 >> FSH;                       // uniform (scalar)
        int c0 = (k0 & ((1 << FSH) - 1)) + lq * 8;
        int dy = tap / 18, dx = tap - dy * 18;
        bfX = *(const h8*)(Wz + ((size_t)((k0 >> 3) + lq) * 16 + lr) * 8);
        long doff = ((long)(dy * FHP + dx) << FSH) + c0;
#pragma unroll
        for (int i = 0; i < TW; ++i)
            avX[i] = *(const h8*)(pb[i] + doff);
    };
    auto mfma_step = [&](h8* avX, h8 bfX) {
#pragma unroll
        for (int i = 0; i < TW; ++i)
            acc[i] = __builtin_amdgcn_mfma_f32_16x16x32_f16(avX[i], bfX, acc[i], 0, 0, 0);
    };

    h8 avA[TW], avB[TW], bfA, bfB;
    load_step(kstart, avA, bfA);
    int kb = 0;
    for (; kb + 1 < Kc; kb += 2) {
        load_step(kstart + kb + 1, avB, bfB);
        mfma_step(avA, bfA);
        if (kb + 2 < Kc) load_step(kstart + kb + 2, avA, bfA);
        mfma_step(avB, bfB);
    }
    if (kb < Kc) mfma_step(avA, bfA);

    if (lr < 9) {
        int s = lr / 3, p = lr - s * 3;
        float* base = simraw + (size_t)b * 25920
                    + (LVL ? (20736 + (size_t)s * 1728) : ((size_t)s * 6912))
                    + (size_t)p * M;
#pragma unroll
        for (int i = 0; i < TW; ++i) {
            int st = mg * (4 * TW) + wv + 4 * i;
            int row0 = st * 16 + lq * 4;
#pragma unroll
            for (int r = 0; r < 4; ++r) {
                int m = row0 + r;
                if (m < M) atomicAdd(base + m, acc[i][r]);
            }
        }
    }
}

// ---------------------------------------------------------------------------
// Assemble sims -> haloed NHWC f16 interior, stored x 2^-10 (r1 dsc=1024)
// ---------------------------------------------------------------------------
__global__ __launch_bounds__(256) void k_sims(const float* __restrict__ simraw,
    _Float16* __restrict__ simshI)
{
    int idx = blockIdx.x * 256 + threadIdx.x;
    if (idx >= 110592) return;
    int scat = idx & 7;
    int rest = idx >> 3;
    int x = rest % 48, y = (rest / 48) % 48;
    int p = (rest / 2304) % 3, b = rest / 6912;
    float v = 0.f;
    if (scat < 6) {
        int lvl = scat / 3, s = scat % 3;
        if (lvl == 0) {
            v = simraw[(size_t)b * 25920 + (size_t)s * 6912 + (size_t)p * 2304 + y * 48 + x];
        } else {
            const float* src = simraw + (size_t)b * 25920 + 20736 + (size_t)s * 1728
                                      + (size_t)p * 576;
            float sy = (y + 0.5f) * 0.5f - 0.5f; sy = fminf(fmaxf(sy, 0.f), 23.f);
            int y0 = (int)floorf(sy); float ty = sy - y0; int y1 = min(y0 + 1, 23);
            float sx = (x + 0.5f) * 0.5f - 0.5f; sx = fminf(fmaxf(sx, 0.f), 23.f);
            int x0 = (int)floorf(sx); float tx = sx - x0; int x1 = min(x0 + 1, 23);
            v = (1.f - ty) * ((1.f - tx) * src[y0 * 24 + x0] + tx * src[y0 * 24 + x1])
              +        ty  * ((1.f - tx) * src[y1 * 24 + x0] + tx * src[y1 * 24 + x1]);
        }
    }
    int n = b * 3 + p;
    simshI[((size_t)n * 32768 + ((size_t)y * 64 + x) * 8) + scat]
        = (_Float16)(v * 0.0009765625f);   // x 2^-10
}

// ---------------------------------------------------------------------------
// align-corners 2x bilinear upsample, NHWC f16 (h8 vectors), strided in/out
// ---------------------------------------------------------------------------
__global__ __launch_bounds__(256) void k_up2acH(const h8* __restrict__ inI,
    int inWp, long inStride, h8* __restrict__ outI, int outWp, long outStride,
    int N_, int Hin, int Win, int Cg)
{
    int Hout = 2 * Hin, Wout = 2 * Win;
    size_t total = (size_t)N_ * Hout * Wout * Cg;
    size_t idx = (size_t)blockIdx.x * 256 + threadIdx.x;
    if (idx >= total) return;
    int cg = (int)(idx % Cg);
    size_t r = idx / Cg;
    int x = (int)(r % Wout);
    int y = (int)((r / Wout) % Hout);
    int n = (int)(r / ((size_t)Wout * Hout));
    int dh = 2 * Hin - 1, dw = 2 * Win - 1;
    int ay = y * (Hin - 1);
    int y0 = ay / dh; int y1 = min(y0 + 1, Hin - 1);
    float ty = (float)(ay - y0 * dh) / (float)dh;
    int ax = x * (Win - 1);
    int x0 = ax / dw; int x1 = min(x0 + 1, Win - 1);
    float tx = (float)(ax - x0 * dw) / (float)dw;
    const h8* base = inI + (size_t)n * inStride;
    h8 a = base[((size_t)y0 * inWp + x0) * Cg + cg];
    h8 b8 = base[((size_t)y0 * inWp + x1) * Cg + cg];
    h8 c8 = base[((size_t)y1 * inWp + x0) * Cg + cg];
    h8 d8 = base[((size_t)y1 * inWp + x1) * Cg + cg];
    float w00 = (1.f - ty) * (1.f - tx), w01 = (1.f - ty) * tx;
    float w10 = ty * (1.f - tx), w11 = ty * tx;
    h8 o;
#pragma unroll
    for (int j = 0; j < 8; ++j)
        o[j] = (_Float16)(w00 * (float)a[j] + w01 * (float)b8[j]
                        + w10 * (float)c8[j] + w11 * (float)d8[j]);
    outI[(size_t)n * outStride + ((size_t)y * outWp + x) * Cg + cg] = o;
}

// ---------------------------------------------------------------------------
__global__ __launch_bounds__(256) void k_final(const h8* __restrict__ r3h,
    const float* __restrict__ w4, const float* __restrict__ b4,
    const float* __restrict__ w5, const float* __restrict__ b5,
    float* __restrict__ out)
{
    __shared__ float sw4[2048];
    __shared__ float sb4[32];
    __shared__ float sw5[32];
    int tid = threadIdx.x;
    for (int i = tid; i < 2048; i += 256) sw4[i] = w4[i];
    if (tid < 32) { sb4[tid] = b4[tid]; sw5[tid] = w5[tid]; }
    __syncthreads();
    int idx = blockIdx.x * 256 + tid;
    int x = idx % 384, y = (idx / 384) % 384, b = idx / 147456;
    int ay = y * 191; int y0 = ay / 383; int y1 = min(y0 + 1, 191);
    float ty = (float)(ay - y0 * 383) / 383.f;
    int ax = x * 191; int x0 = ax / 383; int x1 = min(x0 + 1, 191);
    float tx = (float)(ax - x0 * 383) / 383.f;
    float w00 = (1.f - ty) * (1.f - tx), w01 = (1.f - ty) * tx;
    float w10 = ty * (1.f - tx), w11 = ty * tx;
    float best = 0.f;
    for (int p = 0; p < 3; ++p) {
        int n = b * 3 + p;
        float acc[32];
#pragma unroll
        for (int co = 0; co < 32; ++co) acc[co] = sb4[co];
        const h8* rb = r3h + (size_t)n * 36864 * 8;
        for (int cg = 0; cg < 8; ++cg) {
            h8 a00 = rb[(size_t)(y0 * 192 + x0) * 8 + cg];
            h8 a01 = rb[(size_t)(y0 * 192 + x1) * 8 + cg];
            h8 a10 = rb[(size_t)(y1 * 192 + x0) * 8 + cg];
            h8 a11 = rb[(size_t)(y1 * 192 + x1) * 8 + cg];
#pragma unroll
            for (int jj = 0; jj < 8; ++jj) {
                float v = (w00 * (float)a00[jj] + w01 * (float)a01[jj]
                         + w10 * (float)a10[jj] + w11 * (float)a11[jj]) * 64.f;
                int ci = cg * 8 + jj;
#pragma unroll
                for (int co = 0; co < 32; ++co)
                    acc[co] = fmaf(sw4[co * 64 + ci], v, acc[co]);
            }
        }
        float s5 = b5[0];
#pragma unroll
        for (int co = 0; co < 32; ++co)
            s5 = fmaf(fmaxf(acc[co], 0.f), sw5[co], s5);
        s5 = fmaxf(s5, 0.f);
        best = fmaxf(best, s5);
    }
    out[idx] = best;
}

// ---------------------------------------------------------------------------
extern "C" void kernel_launch(void* const* d_in, const int* in_sizes, int n_in,
                              void* d_out, int out_size, void* d_ws, size_t ws_size,
                              hipStream_t stream)
{
    (void)in_sizes; (void)n_in; (void)out_size; (void)ws_size;
    const float* images = (const float*)d_in[0];
    const float* tlbrs  = (const float*)d_in[1];
    const float* fw1 = (const float*)d_in[2];
    const float* fw2 = (const float*)d_in[3];
    const float* fw3 = (const float*)d_in[4];
    const float* fw4 = (const float*)d_in[5];
    const float* rw1 = (const float*)d_in[6];
    const float* rb1 = (const float*)d_in[7];
    const float* rw2 = (const float*)d_in[8];
    const float* rb2 = (const float*)d_in[9];
    const float* rw3 = (const float*)d_in[10];
    const float* rb3 = (const float*)d_in[11];
    const float* rw4 = (const float*)d_in[12];
    const float* rb4 = (const float*)d_in[13];
    const float* rw5 = (const float*)d_in[14];
    const float* rb5 = (const float*)d_in[15];
    float* wsf = (float*)d_ws;
    int* meta = (int*)d_ws;
    float* out = (float*)d_out;
    _Float16* wb = (_Float16*)(wsf + OFF_WB);

    // interior pointers (halo offsets)
    _Float16* imhI   = (_Float16*)(wsf + IMH)  + (8 * 400 + 8) * 8;
    _Float16* b1hI   = (_Float16*)(wsf + B1H)  + (8 * 208 + 8) * 64;
    _Float16* b2hI   = (_Float16*)(wsf + B2H)  + (8 * 112 + 8) * 256;
    _Float16* f3hI   = (_Float16*)(wsf + F3H)  + (12 * 72 + 12) * 512;
    _Float16* f4hI   = (_Float16*)(wsf + F4H)  + (12 * 48 + 12) * 1024;
    _Float16* simshI = (_Float16*)(wsf + OFF_SIMSH) + (8 * 64 + 8) * 8;
    _Float16* r1hI   = (_Float16*)(wsf + R1H)  + (8 * 64 + 8) * 200;
    _Float16* u1hI   = (_Float16*)(wsf + U1H)  + (8 * 112 + 8) * 200;
    _Float16* r2h    = (_Float16*)(wsf + R2H);
    _Float16* u2hI   = (_Float16*)(wsf + U2H)  + (8 * 208 + 8) * 128;
    _Float16* r3h    = (_Float16*)(wsf + R3H);
    _Float16* wsim   = (_Float16*)(wsf + WSIM);

    const float INV64 = 1.f / 64.f;

    hipLaunchKernelGGL(k_halos1, dim3(1728, 5), dim3(256), 0, stream, wsf);
    hipLaunchKernelGGL(k_meta, dim3(1), dim3(64), 0, stream, tlbrs, meta);
    hipLaunchKernelGGL(k_im2hwc, dim3(9216), dim3(256), 0, stream, images,
        (_Float16*)(wsf + IMH));

    // ---- weight banks ----
    hipLaunchKernelGGL(k_wprepH, dim3(104), dim3(256), 0, stream,
        fw1, wb + WB1, 3, 49, 8, 64, 64, 26624);
    hipLaunchKernelGGL(k_wprepH, dim3(576), dim3(256), 0, stream,
        fw2, wb + WB2, 64, 9, 64, 256, 256, 147456);
    hipLaunchKernelGGL(k_wprepH, dim3(4608), dim3(256), 0, stream,
        fw3, wb + WB3, 256, 9, 256, 512, 512, 1179648);
    hipLaunchKernelGGL(k_wprepH, dim3(18432), dim3(256), 0, stream,
        fw4, wb + WB4, 512, 9, 512, 1024, 1024, 4718592);
    hipLaunchKernelGGL(k_wprepH, dim3(416), dim3(256), 0, stream,
        rw1, wb + WR1, 6, 49, 8, 196, 256, 106496);
    hipLaunchKernelGGL(k_wprepH, dim3(2512), dim3(256), 0, stream,
        rw2, wb + WR2, 196, 25, 200, 128, 128, 643072);
    hipLaunchKernelGGL(k_wprepH, dim3(288), dim3(256), 0, stream,
        rw3, wb + WR3, 128, 9, 128, 64, 64, 73728);

    // ---- backbone (NT=4, BM = 64*MT) ----
    hipLaunchKernelGGL((k_convH<49, 7, 2, 8, 2>), dim3(288, 1, 2), dim3(256), 0, stream,
        imhI, 400, 1280000L, wb + WB1, (const float*)nullptr,
        b1hI, 208, 2768896L, 64, 64, 192, 3, 416, 64, 1.f, 1.f);
    hipLaunchKernelGGL((k_convH<9, 3, 2, 64, 2>), dim3(72, 4, 2), dim3(256), 0, stream,
        b1hI, 208, 2768896L, wb + WB2, (const float*)nullptr,
        b2hI, 112, 3211264L, 256, 256, 96, 1, 576, 256, 1.f, 1.f);
    hipLaunchKernelGGL((k_convH<9, 3, 2, 256, 2>), dim3(18, 8, 2), dim3(256), 0, stream,
        b2hI, 112, 3211264L, wb + WB3, (const float*)nullptr,
        f3hI, 72, 2654208L, 512, 512, 48, 1, 2304, 512, 1.f, 1.f);
    hipLaunchKernelGGL((k_convH<9, 3, 2, 512, 1>), dim3(9, 16, 2), dim3(256), 0, stream,
        f3hI, 72, 2654208L, wb + WB4, (const float*)nullptr,
        f4hI, 48, 2359296L, 1024, 1024, 24, 1, 4608, 1024, 1.f, 1.f);

    // ---- feature extraction ----
    hipLaunchKernelGGL(k_praw, dim3(1, 1024, 12), dim3(256), 0, stream,
        f3hI, f4hI, meta, wsf + PRAW);
    hipLaunchKernelGGL(k_psc, dim3(2, 1024, 36), dim3(256), 0, stream,
        wsf + PRAW, meta, wsf + PSC);
    hipLaunchKernelGGL(k_wsim, dim3(20736, 1, 4), dim3(256), 0, stream,
        wsf + PSC, meta, wsim);
    hipLaunchKernelGGL(k_fill0, dim3(203), dim3(256), 0, stream,
        wsf + SIMRAW, 51840);
    hipLaunchKernelGGL((k_simL<6, 48, 72, 9, false>), dim3(6, 96, 2), dim3(256), 0, stream,
        f3hI, 2654208L, wsim, wsf + SIMRAW, 54);
    hipLaunchKernelGGL((k_simL<3, 24, 48, 10, true>), dim3(3, 144, 2), dim3(256), 0, stream,
        f4hI, 2359296L, wsim + 2654208, wsf + SIMRAW, 72);
    hipLaunchKernelGGL(k_sims, dim3(432), dim3(256), 0, stream,
        wsf + SIMRAW, simshI);
    // phase-2 halos (f3h/f4h/PSC/WSIM dead from here)
    hipLaunchKernelGGL(k_halos2, dim3(2400, 4), dim3(256), 0, stream, wsf);

    // ---- count regressor ----
    hipLaunchKernelGGL((k_convH<49, 7, 1, 8, 2>), dim3(18, 4, 6), dim3(256), 0, stream,
        simshI, 64, 32768L, wb + WR1, rb1,
        r1hI, 64, 819200L, 196, 256, 48, 3, 416, 200, 1024.f, INV64);
    hipLaunchKernelGGL(k_up2acH, dim3(5400), dim3(256), 0, stream,
        (const h8*)r1hI, 64, 102400L, (h8*)u1hI, 112, 313600L, 6, 48, 48, 25);
    hipLaunchKernelGGL((k_convH<25, 5, 1, 200, 2>), dim3(72, 2, 6), dim3(256), 0, stream,
        u1hI, 112, 2508800L, wb + WR2, rb2,
        r2h, 96, 1179648L, 128, 128, 96, 2, 5024, 128, 64.f, INV64);
    hipLaunchKernelGGL(k_up2acH, dim3(13824), dim3(256), 0, stream,
        (const h8*)r2h, 96, 147456L, (h8*)u2hI, 208, 692224L, 6, 96, 96, 16);
    hipLaunchKernelGGL((k_convH<9, 3, 1, 128, 2>), dim3(288, 1, 6), dim3(256), 0, stream,
        u2hI, 208, 5537792L, wb + WR3, rb3,
        r3h, 192, 2359296L, 64, 64, 192, 1, 1152, 64, 64.f, INV64);
    hipLaunchKernelGGL(k_final, dim3(1152), dim3(256), 0, stream,
        (const h8*)r3h, rw4, rb4, rw5, rb5, out);
}

// Round 14
// 994.639 us; speedup vs baseline: 1.3357x; 1.2230x over previous
//
#include <hip/hip_runtime.h>
#include <math.h>

typedef _Float16 h8 __attribute__((ext_vector_type(8)));
typedef float f4 __attribute__((ext_vector_type(4)));

// ---------------------------------------------------------------------------
// Workspace layout (float units). All activations NHWC f16 with spatial HALO
// (zero-filled). Scale chain: sims x2^-10 (r1 dsc=1024); regressor acts x1/64
// (consumers dsc=64); k_final x64. All pow2 (exact).
// Sim K-order: k = (cb, tap, ci) with 16-ch blocks -> k_simS stages fm slice
// in LDS once and runs the whole K-loop from LDS.
// ---------------------------------------------------------------------------
static const size_t OFF_SIMSH = 256;       // (6, 64x64, 8) h halo8
static const size_t OFF_WB    = 98560;     // weight banks, 6895616 h
static const size_t ARENA     = 3546368;
// phase 1
static const size_t IMH  = 3546368;    // (2,400x400,8) h halo8
static const size_t B1H  = 4826368;    // (2,208x208,64) halo8
static const size_t B2H  = 7595264;    // (2,112x112,256) halo8
static const size_t F3H  = 10806528;   // (2,72x72,512) halo12
static const size_t F4H  = 13460736;   // (2,48x48,1024) halo12
static const size_t PRAW = 15820032;   // fp32 2359296
static const size_t PSC  = 18179328;   // fp32 8957952
static const size_t SIMRAW = 27137280; // fp32 51840
static const size_t WSIM = 27189120;   // f16 15925248 h
// phase 2 (reuses arena after k_sims)
static const size_t R1H = 3546368;     // (6,64x64,200) halo8
static const size_t U1H = 6003968;     // (6,112x112,200) halo8
static const size_t R2H = 13530368;    // (6,96x96,128) no halo
static const size_t U2H = 17069312;    // (6,208x208,128) halo8
static const size_t R3H = 33676544;    // (6,192x192,64) no halo

// f16-unit offsets inside WB bank
static const size_t WB1 = 0;
static const size_t WB2 = 26624;
static const size_t WB3 = 174080;
static const size_t WB4 = 1353728;
static const size_t WR1 = 6072320;
static const size_t WR2 = 6178816;
static const size_t WR3 = 6821888;

// ---------------------------------------------------------------------------
__global__ __launch_bounds__(64) void k_meta(const float* __restrict__ tlbrs,
                                             int* __restrict__ meta)
{
    if (threadIdx.x != 0 || blockIdx.x != 0) return;
    const double SC[3] = {1.0, 0.9, 1.1};
    for (int b = 0; b < 2; ++b)
        for (int lvl = 0; lvl < 2; ++lvl) {
            int FH = lvl ? 24 : 48;
            float scaling = lvl ? 16.f : 8.f;
            int base = (b * 2 + lvl) * 32;
            int PH = 0, PW = 0;
            for (int p = 0; p < 3; ++p) {
                const float* t4 = tlbrs + (b * 3 + p) * 4;
                float st = t4[0] / scaling, sl = t4[1] / scaling;
                float sb = t4[2] / scaling, sr = t4[3] / scaling;
                int top  = (int)fmaxf(floorf(st), 0.f);
                int left = (int)fmaxf(floorf(sl), 0.f);
                int bot  = (int)fminf(ceilf(sb) + 1.f, (float)FH);
                int rgt  = (int)fminf(ceilf(sr) + 1.f, (float)FH);
                meta[base + p * 4 + 0] = top;
                meta[base + p * 4 + 1] = left;
                meta[base + p * 4 + 2] = bot;
                meta[base + p * 4 + 3] = rgt;
                PH = max(PH, bot - top);
                PW = max(PW, rgt - left);
            }
            meta[base + 12] = PH;
            meta[base + 13] = PW;
            for (int s = 0; s < 3; ++s) {
                int PHs = (int)ceil((double)PH * SC[s]);
                int PWs = (int)ceil((double)PW * SC[s]);
                if (PHs < 1) PHs = PH;
                if (PWs < 1) PWs = PW;
                meta[base + 14 + s * 2] = PHs;
                meta[base + 15 + s * 2] = PWs;
            }
        }
}

// ---------------------------------------------------------------------------
__device__ __forceinline__ void halo_zero(h8* base, int Hp, int Wp, int halo,
                                          int Cg, int N)
{
    int inner = Hp - 2 * halo;
    int frame = Hp * Wp - inner * inner;
    long total = (long)N * frame * Cg;
    long idx = (long)blockIdx.x * 256 + threadIdx.x;
    if (idx >= total) return;
    int cg = (int)(idx % Cg);
    long r = idx / Cg;
    int f = (int)(r % frame);
    int n = (int)(r / frame);
    int topN = halo * Wp;
    int y, x;
    if (f < topN) { y = f / Wp; x = f % Wp; }
    else if (f < 2 * topN) { int f2 = f - topN; y = Hp - halo + f2 / Wp; x = f2 % Wp; }
    else {
        int f3 = f - 2 * topN;
        int row = f3 / (2 * halo), rr = f3 - row * (2 * halo);
        y = halo + row;
        x = rr < halo ? rr : Wp - 2 * halo + rr;
    }
    h8 z;
#pragma unroll
    for (int j = 0; j < 8; ++j) z[j] = (_Float16)0.f;
    base[((long)n * Hp * Wp + (long)y * Wp + x) * Cg + cg] = z;
}

__global__ __launch_bounds__(256) void k_halos1(float* wsf)
{
    switch (blockIdx.y) {
    case 0: halo_zero((h8*)(wsf + IMH), 400, 400, 8, 1, 2); break;
    case 1: halo_zero((h8*)(wsf + B1H), 208, 208, 8, 8, 2); break;
    case 2: halo_zero((h8*)(wsf + B2H), 112, 112, 8, 32, 2); break;
    case 3: halo_zero((h8*)(wsf + F3H), 72, 72, 12, 64, 2); break;
    default: halo_zero((h8*)(wsf + F4H), 48, 48, 12, 128, 2); break;
    }
}

__global__ __launch_bounds__(256) void k_halos2(float* wsf)
{
    switch (blockIdx.y) {
    case 0: halo_zero((h8*)(wsf + OFF_SIMSH), 64, 64, 8, 1, 6); break;
    case 1: halo_zero((h8*)(wsf + R1H), 64, 64, 8, 25, 6); break;
    case 2: halo_zero((h8*)(wsf + U1H), 112, 112, 8, 25, 6); break;
    default: halo_zero((h8*)(wsf + U2H), 208, 208, 8, 16, 6); break;
    }
}

// ---------------------------------------------------------------------------
__global__ __launch_bounds__(256) void k_im2hwc(const float* __restrict__ img,
    _Float16* __restrict__ o)
{
    int idx = blockIdx.x * 256 + threadIdx.x;
    if (idx >= 2359296) return;
    int c = idx & 7;
    int pix = (idx >> 3) % 147456;
    int b = (idx >> 3) / 147456;
    int y = pix / 384, x = pix - y * 384;
    float v = (c < 3) ? img[((size_t)b * 3 + c) * 147456 + pix] : 0.f;
    o[((size_t)b * 1280000 + ((size_t)(y + 8) * 400 + (x + 8)) * 8) + c] = (_Float16)v;
}

// ---------------------------------------------------------------------------
__global__ __launch_bounds__(256) void k_wprepH(const float* __restrict__ w,
    _Float16* __restrict__ wB, int Cin, int KKt, int Cinp, int Cout, int Coutp,
    int total)
{
    int idx = blockIdx.x * 256 + threadIdx.x;
    if (idx >= total) return;
    int j = idx & 7;
    int co = (idx >> 3) % Coutp;
    int kq = idx / (8 * Coutp);
    int k = kq * 8 + j;
    int tap = k / Cinp, cip = k - tap * Cinp;
    float v = 0.f;
    if (tap < KKt && cip < Cin && co < Cout)
        v = w[((size_t)co * Cin + cip) * KKt + tap];
    wB[idx] = (_Float16)v;
}

// ---------------------------------------------------------------------------
// Halo NHWC implicit-GEMM conv, NT=4 outer product, BM = 64*MT, BN = 64.
// No bounds checks (halo + zero-padded wB). SW-pipelined depth 1, LDS-free.
// ---------------------------------------------------------------------------
template<int KK, int KW, int S, int CINP, int MT>
__global__ __launch_bounds__(256) void k_convH(
    const _Float16* __restrict__ inI, int Winp, long inStride,
    const _Float16* __restrict__ wB, const float* __restrict__ bias,
    _Float16* __restrict__ outI, int Wop, long outStride,
    int Cout, int Coutp, int Wout, int pad, int Kpad, int storeC,
    float dsc, float osc)
{
    const int tid = threadIdx.x;
    const int n_img = blockIdx.z;
    const int m0 = blockIdx.x * (MT * 64);
    const int co0 = blockIdx.y * 64;
    const _Float16* inb = inI + (size_t)n_img * inStride;

    const int wv = tid >> 6, lane = tid & 63;
    const int lq = lane >> 4, lr = lane & 15;

    const _Float16* pb[MT];
#pragma unroll
    for (int mt = 0; mt < MT; ++mt) {
        int m = m0 + (wv * MT + mt) * 16 + lr;
        int y = m / Wout, x = m - y * Wout;
        pb[mt] = inb + ((long)(y * S - pad) * Winp + (x * S - pad)) * CINP;
    }
    const _Float16* wbc = wB + (size_t)(co0 + lr) * 8;

    f4 acc[MT][4];
#pragma unroll
    for (int i = 0; i < MT; ++i)
#pragma unroll
        for (int j = 0; j < 4; ++j) { f4 z = {0.f, 0.f, 0.f, 0.f}; acc[i][j] = z; }

    const int Ksteps = Kpad >> 5;

    auto load_step = [&](int kb, h8* afX, h8* bfX) {
        int k0 = kb * 32 + lq * 8;
        int tap = k0 / CINP;
        int ci0 = k0 - tap * CINP;
        int dy = tap / KW, dx = tap - dy * KW;
        size_t kq = (size_t)(kb * 4 + lq) * Coutp;
#pragma unroll
        for (int nt = 0; nt < 4; ++nt)
            bfX[nt] = *(const h8*)(wbc + (kq + nt * 16) * 8);
        int doff = (dy * Winp + dx) * CINP + ci0;
#pragma unroll
        for (int mt = 0; mt < MT; ++mt)
            afX[mt] = *(const h8*)(pb[mt] + doff);
    };
    auto mfma_step = [&](h8* afX, h8* bfX) {
#pragma unroll
        for (int mt = 0; mt < MT; ++mt)
#pragma unroll
            for (int nt = 0; nt < 4; ++nt)
                acc[mt][nt] = __builtin_amdgcn_mfma_f32_16x16x32_f16(
                    afX[mt], bfX[nt], acc[mt][nt], 0, 0, 0);
    };

    h8 afA[MT], bfA[4], afB[MT], bfB[4];
    load_step(0, afA, bfA);
    int kb = 0;
    for (; kb + 1 < Ksteps; kb += 2) {
        load_step(kb + 1, afB, bfB);
        mfma_step(afA, bfA);
        if (kb + 2 < Ksteps) load_step(kb + 2, afA, bfA);
        mfma_step(afB, bfB);
    }
    if (kb < Ksteps) mfma_step(afA, bfA);

    _Float16* ob = outI + (size_t)n_img * outStride;
#pragma unroll
    for (int nt = 0; nt < 4; ++nt) {
        int co = co0 + nt * 16 + lr;
        if (co >= storeC) continue;
        bool valid = co < Cout;
        float bv = (bias && valid) ? bias[co] : 0.f;
#pragma unroll
        for (int mt = 0; mt < MT; ++mt) {
#pragma unroll
            for (int reg = 0; reg < 4; ++reg) {
                int m = m0 + (wv * MT + mt) * 16 + lq * 4 + reg;
                int y = m / Wout, x = m - y * Wout;
                float v = valid
                    ? fmaxf(fmaf(acc[mt][nt][reg], dsc, bv), 0.f) * osc : 0.f;
                ob[((long)y * Wop + x) * storeC + co] = (_Float16)v;
            }
        }
    }
}

// ---------------------------------------------------------------------------
__global__ __launch_bounds__(256) void k_praw(const _Float16* __restrict__ f3hI,
    const _Float16* __restrict__ f4hI, const int* __restrict__ meta,
    float* __restrict__ praw)
{
    int z = blockIdx.z;
    int p = z % 3, m = z / 3, lvl = m % 2, b = m / 2;
    int c = blockIdx.y;
    int FC = lvl ? 1024 : 512;
    if (c >= FC) return;
    int FHp = lvl ? 48 : 72;
    int fsh = lvl ? 10 : 9;
    const int* mb = meta + m * 32;
    int PH = mb[12], PW = mb[13];
    int oy = threadIdx.x / 16, ox = threadIdx.x % 16;
    if (oy >= PH || ox >= PW) return;
    int top = mb[p * 4 + 0], left = mb[p * 4 + 1];
    int bot = mb[p * 4 + 2], rgt = mb[p * 4 + 3];
    int h = bot - top, w = rgt - left;
    const _Float16* fm = lvl ? (f4hI + (size_t)b * 2359296)
                             : (f3hI + (size_t)b * 2654208);
    float sy = ((oy + 0.5f) * h) / PH - 0.5f;
    sy = fminf(fmaxf(sy, 0.f), (float)(h - 1));
    int y0 = (int)floorf(sy); float ty = sy - y0; int y1 = min(y0 + 1, h - 1);
    float sx = ((ox + 0.5f) * w) / PW - 0.5f;
    sx = fminf(fmaxf(sx, 0.f), (float)(w - 1));
    int x0 = (int)floorf(sx); float tx = sx - x0; int x1 = min(x0 + 1, w - 1);
    float v00 = (float)fm[((size_t)((top + y0) * FHp + (left + x0)) << fsh) + c];
    float v01 = (float)fm[((size_t)((top + y0) * FHp + (left + x1)) << fsh) + c];
    float v10 = (float)fm[((size_t)((top + y1) * FHp + (left + x0)) << fsh) + c];
    float v11 = (float)fm[((size_t)((top + y1) * FHp + (left + x1)) << fsh) + c];
    float v = (1.f - ty) * ((1.f - tx) * v00 + tx * v01)
            +        ty  * ((1.f - tx) * v10 + tx * v11);
    size_t base = (size_t)(b * 1179648 + (lvl ? 393216 : 0)) + ((size_t)p * FC + c) * 256;
    praw[base + oy * 16 + ox] = v;
}

// ---------------------------------------------------------------------------
__global__ __launch_bounds__(256) void k_psc(const float* __restrict__ praw,
    const int* __restrict__ meta, float* __restrict__ psc)
{
    int z = blockIdx.z;
    int p = z % 3, s = (z / 3) % 3, lvl = (z / 9) % 2, b = z / 18;
    int c = blockIdx.y;
    int FC = lvl ? 1024 : 512;
    if (c >= FC) return;
    const int* mb = meta + (b * 2 + lvl) * 32;
    int PH = mb[12], PW = mb[13];
    int PHs = mb[14 + s * 2], PWs = mb[15 + s * 2];
    int idx = blockIdx.x * 256 + threadIdx.x;
    int ys = idx / 18, xs = idx % 18;
    if (ys >= PHs || xs >= PWs) return;
    const float* src = praw + (size_t)(b * 1179648 + (lvl ? 393216 : 0))
                            + ((size_t)p * FC + c) * 256;
    float sy = ((ys + 0.5f) * PH) / PHs - 0.5f;
    sy = fminf(fmaxf(sy, 0.f), (float)(PH - 1));
    int y0 = (int)floorf(sy); float ty = sy - y0; int y1 = min(y0 + 1, PH - 1);
    float sx = ((xs + 0.5f) * PW) / PWs - 0.5f;
    sx = fminf(fmaxf(sx, 0.f), (float)(PW - 1));
    int x0 = (int)floorf(sx); float tx = sx - x0; int x1 = min(x0 + 1, PW - 1);
    float v = (1.f - ty) * ((1.f - tx) * src[y0 * 16 + x0] + tx * src[y0 * 16 + x1])
            +        ty  * ((1.f - tx) * src[y1 * 16 + x0] + tx * src[y1 * 16 + x1]);
    size_t base = (size_t)b * 4478976 + (lvl ? (1492992 + (size_t)s * 995328)
                                             : ((size_t)s * 497664));
    psc[base + ((size_t)p * FC + c) * 324 + ys * 18 + xs] = v;
}

__global__ __launch_bounds__(256) void k_fill0(float* p, int n)
{
    int i = blockIdx.x * 256 + threadIdx.x;
    if (i < n) p[i] = 0.f;
}

// ---------------------------------------------------------------------------
// Sim filter bank, NEW k-order k = (cb, tap, ci) with 16-ch blocks:
// Wz[kq][n(16)][8] f16, k = cb*(324*16) + tap*16 + ci.
// ---------------------------------------------------------------------------
__global__ __launch_bounds__(256) void k_wsim(const float* __restrict__ psc,
    const int* __restrict__ meta, _Float16* __restrict__ W)
{
    int z = blockIdx.z;                 // b*2+lvl
    int lvl = z & 1, b = z >> 1;
    int FC = lvl ? 1024 : 512;
    int total = FC * 324 * 16;
    int e = blockIdx.x * 256 + threadIdx.x;
    if (e >= total) return;
    _Float16* Wz = W + (size_t)b * 7962624 + (lvl ? 2654208 : 0);
    int j = e & 7, n = (e >> 3) & 15, kq = e >> 7;
    int k = kq * 8 + j;
    int ci = k & 15;
    int tapcb = k >> 4;
    int tap = tapcb % 324;
    int cb = tapcb / 324;
    int c = cb * 16 + ci;
    int rr = tap / 18, cc = tap - rr * 18;
    float v = 0.f;
    if (n < 9) {
        int s = n / 3, p = n % 3;
        const int* mb = meta + z * 32;
        int PHs = mb[14 + s * 2], PWs = mb[15 + s * 2];
        int ky = rr - (9 - (PHs >> 1));
        int kx = cc - (9 - (PWs >> 1));
        if ((unsigned)ky < (unsigned)PHs && (unsigned)kx < (unsigned)PWs) {
            size_t base = (size_t)b * 4478976 + (lvl ? (1492992 + (size_t)s * 995328)
                                                     : ((size_t)s * 497664));
            v = psc[base + ((size_t)p * FC + c) * 324 + ky * 18 + kx];
        }
    }
    Wz[e] = (_Float16)v;
}

// ---------------------------------------------------------------------------
// Sim GEMM with LDS-staged fm slice: grid (mg, cb, b). Block stages the fm
// rows needed by its pixel band for ONE 16-channel block (layout
// As[half][row][col][8], 2-way-conflict-light), then runs all 324 taps
// (162 K=32 steps: 2 taps x 16 ch) entirely from LDS + 1 global B-load/step.
// Split-K over cb via fp32 atomicAdd into simraw.
// ---------------------------------------------------------------------------
template<int TW, int FH, int FHP, int FC, int SROWS, int SCOLSU, bool LVL>
__global__ __launch_bounds__(256) void k_simS(
    const _Float16* __restrict__ fI, long fStride,
    const _Float16* __restrict__ Wb, float* __restrict__ simraw)
{
    __shared__ __align__(16) _Float16 As[2 * SROWS * SCOLSU * 8];
    const int M = FH * FH;
    const int PIX = TW * 64;
    const int b = blockIdx.z;
    const int mg = blockIdx.x;
    const int cb = blockIdx.y;
    const _Float16* fm = fI + (size_t)b * fStride;
    const _Float16* Wz = Wb + (size_t)b * 7962624 + (LVL ? 2654208 : 0)
                       + (size_t)cb * 82944;   // cb*648 kq * 128 halfs
    const int tid = threadIdx.x;
    const int y0row = (mg * PIX) / FH;

    // stage fm slice: rows y0row-9 .. y0row+SROWS-10, cols -9 .. SCOLSU-10
    const int count = 2 * SROWS * SCOLSU;
    for (int idx = tid; idx < count; idx += 256) {
        int half = idx / (SROWS * SCOLSU);
        int rem = idx - half * (SROWS * SCOLSU);
        int row = rem / SCOLSU, col = rem - row * SCOLSU;
        const _Float16* src = fm + ((long)(y0row + row - 9) * FHP + (col - 9)) * FC
                            + cb * 16 + half * 8;
        *(h8*)&As[idx * 8] = *(const h8*)src;
    }
    __syncthreads();

    const int wv = tid >> 6, lane = tid & 63;
    const int lq = lane >> 4, lr = lane & 15;
    int abase[TW];
#pragma unroll
    for (int i = 0; i < TW; ++i) {
        int st = mg * (4 * TW) + wv + 4 * i;
        int m = st * 16 + lr;
        int py = m / FH - y0row, px = m - (m / FH) * FH;
        abase[i] = ((lq & 1) * SROWS + py) * SCOLSU + px;
    }
    const int thalf = lq >> 1;           // 0 -> even tap, 1 -> odd tap

    f4 acc[TW];
#pragma unroll
    for (int i = 0; i < TW; ++i) { f4 z = {0.f, 0.f, 0.f, 0.f}; acc[i] = z; }

    auto load_step = [&](int step, h8* avX, h8& bfX) {
        int tap = step * 2 + thalf;
        int dy = tap / 18, dx = tap - dy * 18;
        bfX = *(const h8*)(Wz + ((size_t)(step * 4 + lq) * 16 + lr) * 8);
        int doff = dy * SCOLSU + dx;
#pragma unroll
        for (int i = 0; i < TW; ++i)
            avX[i] = *(const h8*)&As[(size_t)(abase[i] + doff) * 8];
    };
    auto mfma_step = [&](h8* avX, h8 bfX) {
#pragma unroll
        for (int i = 0; i < TW; ++i)
            acc[i] = __builtin_amdgcn_mfma_f32_16x16x32_f16(avX[i], bfX, acc[i], 0, 0, 0);
    };

    h8 avA[TW], avB[TW], bfA, bfB;
    load_step(0, avA, bfA);
    int kb = 0;
    for (; kb + 1 < 162; kb += 2) {
        load_step(kb + 1, avB, bfB);
        mfma_step(avA, bfA);
        if (kb + 2 < 162) load_step(kb + 2, avA, bfA);
        mfma_step(avB, bfB);
    }
    if (kb < 162) mfma_step(avA, bfA);

    if (lr < 9) {
        int s = lr / 3, p = lr - s * 3;
        float* base = simraw + (size_t)b * 25920
                    + (LVL ? (20736 + (size_t)s * 1728) : ((size_t)s * 6912))
                    + (size_t)p * M;
#pragma unroll
        for (int i = 0; i < TW; ++i) {
            int st = mg * (4 * TW) + wv + 4 * i;
            int row0 = st * 16 + lq * 4;
#pragma unroll
            for (int r = 0; r < 4; ++r) {
                int m = row0 + r;
                if (m < M) atomicAdd(base + m, acc[i][r]);
            }
        }
    }
}

// ---------------------------------------------------------------------------
__global__ __launch_bounds__(256) void k_sims(const float* __restrict__ simraw,
    _Float16* __restrict__ simshI)
{
    int idx = blockIdx.x * 256 + threadIdx.x;
    if (idx >= 110592) return;
    int scat = idx & 7;
    int rest = idx >> 3;
    int x = rest % 48, y = (rest / 48) % 48;
    int p = (rest / 2304) % 3, b = rest / 6912;
    float v = 0.f;
    if (scat < 6) {
        int lvl = scat / 3, s = scat % 3;
        if (lvl == 0) {
            v = simraw[(size_t)b * 25920 + (size_t)s * 6912 + (size_t)p * 2304 + y * 48 + x];
        } else {
            const float* src = simraw + (size_t)b * 25920 + 20736 + (size_t)s * 1728
                                      + (size_t)p * 576;
            float sy = (y + 0.5f) * 0.5f - 0.5f; sy = fminf(fmaxf(sy, 0.f), 23.f);
            int y0 = (int)floorf(sy); float ty = sy - y0; int y1 = min(y0 + 1, 23);
            float sx = (x + 0.5f) * 0.5f - 0.5f; sx = fminf(fmaxf(sx, 0.f), 23.f);
            int x0 = (int)floorf(sx); float tx = sx - x0; int x1 = min(x0 + 1, 23);
            v = (1.f - ty) * ((1.f - tx) * src[y0 * 24 + x0] + tx * src[y0 * 24 + x1])
              +        ty  * ((1.f - tx) * src[y1 * 24 + x0] + tx * src[y1 * 24 + x1]);
        }
    }
    int n = b * 3 + p;
    simshI[((size_t)n * 32768 + ((size_t)y * 64 + x) * 8) + scat]
        = (_Float16)(v * 0.0009765625f);   // x 2^-10
}

// ---------------------------------------------------------------------------
__global__ __launch_bounds__(256) void k_up2acH(const h8* __restrict__ inI,
    int inWp, long inStride, h8* __restrict__ outI, int outWp, long outStride,
    int N_, int Hin, int Win, int Cg)
{
    int Hout = 2 * Hin, Wout = 2 * Win;
    size_t total = (size_t)N_ * Hout * Wout * Cg;
    size_t idx = (size_t)blockIdx.x * 256 + threadIdx.x;
    if (idx >= total) return;
    int cg = (int)(idx % Cg);
    size_t r = idx / Cg;
    int x = (int)(r % Wout);
    int y = (int)((r / Wout) % Hout);
    int n = (int)(r / ((size_t)Wout * Hout));
    int dh = 2 * Hin - 1, dw = 2 * Win - 1;
    int ay = y * (Hin - 1);
    int y0 = ay / dh; int y1 = min(y0 + 1, Hin - 1);
    float ty = (float)(ay - y0 * dh) / (float)dh;
    int ax = x * (Win - 1);
    int x0 = ax / dw; int x1 = min(x0 + 1, Win - 1);
    float tx = (float)(ax - x0 * dw) / (float)dw;
    const h8* base = inI + (size_t)n * inStride;
    h8 a = base[((size_t)y0 * inWp + x0) * Cg + cg];
    h8 b8 = base[((size_t)y0 * inWp + x1) * Cg + cg];
    h8 c8 = base[((size_t)y1 * inWp + x0) * Cg + cg];
    h8 d8 = base[((size_t)y1 * inWp + x1) * Cg + cg];
    float w00 = (1.f - ty) * (1.f - tx), w01 = (1.f - ty) * tx;
    float w10 = ty * (1.f - tx), w11 = ty * tx;
    h8 o;
#pragma unroll
    for (int j = 0; j < 8; ++j)
        o[j] = (_Float16)(w00 * (float)a[j] + w01 * (float)b8[j]
                        + w10 * (float)c8[j] + w11 * (float)d8[j]);
    outI[(size_t)n * outStride + ((size_t)y * outWp + x) * Cg + cg] = o;
}

// ---------------------------------------------------------------------------
__global__ __launch_bounds__(256) void k_final(const h8* __restrict__ r3h,
    const float* __restrict__ w4, const float* __restrict__ b4,
    const float* __restrict__ w5, const float* __restrict__ b5,
    float* __restrict__ out)
{
    __shared__ float sw4[2048];
    __shared__ float sb4[32];
    __shared__ float sw5[32];
    int tid = threadIdx.x;
    for (int i = tid; i < 2048; i += 256) sw4[i] = w4[i];
    if (tid < 32) { sb4[tid] = b4[tid]; sw5[tid] = w5[tid]; }
    __syncthreads();
    int idx = blockIdx.x * 256 + tid;
    int x = idx % 384, y = (idx / 384) % 384, b = idx / 147456;
    int ay = y * 191; int y0 = ay / 383; int y1 = min(y0 + 1, 191);
    float ty = (float)(ay - y0 * 383) / 383.f;
    int ax = x * 191; int x0 = ax / 383; int x1 = min(x0 + 1, 191);
    float tx = (float)(ax - x0 * 383) / 383.f;
    float w00 = (1.f - ty) * (1.f - tx), w01 = (1.f - ty) * tx;
    float w10 = ty * (1.f - tx), w11 = ty * tx;
    float best = 0.f;
    for (int p = 0; p < 3; ++p) {
        int n = b * 3 + p;
        float acc[32];
#pragma unroll
        for (int co = 0; co < 32; ++co) acc[co] = sb4[co];
        const h8* rb = r3h + (size_t)n * 36864 * 8;
        for (int cg = 0; cg < 8; ++cg) {
            h8 a00 = rb[(size_t)(y0 * 192 + x0) * 8 + cg];
            h8 a01 = rb[(size_t)(y0 * 192 + x1) * 8 + cg];
            h8 a10 = rb[(size_t)(y1 * 192 + x0) * 8 + cg];
            h8 a11 = rb[(size_t)(y1 * 192 + x1) * 8 + cg];
#pragma unroll
            for (int jj = 0; jj < 8; ++jj) {
                float v = (w00 * (float)a00[jj] + w01 * (float)a01[jj]
                         + w10 * (float)a10[jj] + w11 * (float)a11[jj]) * 64.f;
                int ci = cg * 8 + jj;
#pragma unroll
                for (int co = 0; co < 32; ++co)
                    acc[co] = fmaf(sw4[co * 64 + ci], v, acc[co]);
            }
        }
        float s5 = b5[0];
#pragma unroll
        for (int co = 0; co < 32; ++co)
            s5 = fmaf(fmaxf(acc[co], 0.f), sw5[co], s5);
        s5 = fmaxf(s5, 0.f);
        best = fmaxf(best, s5);
    }
    out[idx] = best;
}

// ---------------------------------------------------------------------------
extern "C" void kernel_launch(void* const* d_in, const int* in_sizes, int n_in,
                              void* d_out, int out_size, void* d_ws, size_t ws_size,
                              hipStream_t stream)
{
    (void)in_sizes; (void)n_in; (void)out_size; (void)ws_size;
    const float* images = (const float*)d_in[0];
    const float* tlbrs  = (const float*)d_in[1];
    const float* fw1 = (const float*)d_in[2];
    const float* fw2 = (const float*)d_in[3];
    const float* fw3 = (const float*)d_in[4];
    const float* fw4 = (const float*)d_in[5];
    const float* rw1 = (const float*)d_in[6];
    const float* rb1 = (const float*)d_in[7];
    const float* rw2 = (const float*)d_in[8];
    const float* rb2 = (const float*)d_in[9];
    const float* rw3 = (const float*)d_in[10];
    const float* rb3 = (const float*)d_in[11];
    const float* rw4 = (const float*)d_in[12];
    const float* rb4 = (const float*)d_in[13];
    const float* rw5 = (const float*)d_in[14];
    const float* rb5 = (const float*)d_in[15];
    float* wsf = (float*)d_ws;
    int* meta = (int*)d_ws;
    float* out = (float*)d_out;
    _Float16* wb = (_Float16*)(wsf + OFF_WB);

    // interior pointers (halo offsets)
    _Float16* imhI   = (_Float16*)(wsf + IMH)  + (8 * 400 + 8) * 8;
    _Float16* b1hI   = (_Float16*)(wsf + B1H)  + (8 * 208 + 8) * 64;
    _Float16* b2hI   = (_Float16*)(wsf + B2H)  + (8 * 112 + 8) * 256;
    _Float16* f3hI   = (_Float16*)(wsf + F3H)  + (12 * 72 + 12) * 512;
    _Float16* f4hI   = (_Float16*)(wsf + F4H)  + (12 * 48 + 12) * 1024;
    _Float16* simshI = (_Float16*)(wsf + OFF_SIMSH) + (8 * 64 + 8) * 8;
    _Float16* r1hI   = (_Float16*)(wsf + R1H)  + (8 * 64 + 8) * 200;
    _Float16* u1hI   = (_Float16*)(wsf + U1H)  + (8 * 112 + 8) * 200;
    _Float16* r2h    = (_Float16*)(wsf + R2H);
    _Float16* u2hI   = (_Float16*)(wsf + U2H)  + (8 * 208 + 8) * 128;
    _Float16* r3h    = (_Float16*)(wsf + R3H);
    _Float16* wsim   = (_Float16*)(wsf + WSIM);

    const float INV64 = 1.f / 64.f;

    hipLaunchKernelGGL(k_halos1, dim3(1728, 5), dim3(256), 0, stream, wsf);
    hipLaunchKernelGGL(k_meta, dim3(1), dim3(64), 0, stream, tlbrs, meta);
    hipLaunchKernelGGL(k_im2hwc, dim3(9216), dim3(256), 0, stream, images,
        (_Float16*)(wsf + IMH));

    // ---- weight banks ----
    hipLaunchKernelGGL(k_wprepH, dim3(104), dim3(256), 0, stream,
        fw1, wb + WB1, 3, 49, 8, 64, 64, 26624);
    hipLaunchKernelGGL(k_wprepH, dim3(576), dim3(256), 0, stream,
        fw2, wb + WB2, 64, 9, 64, 256, 256, 147456);
    hipLaunchKernelGGL(k_wprepH, dim3(4608), dim3(256), 0, stream,
        fw3, wb + WB3, 256, 9, 256, 512, 512, 1179648);
    hipLaunchKernelGGL(k_wprepH, dim3(18432), dim3(256), 0, stream,
        fw4, wb + WB4, 512, 9, 512, 1024, 1024, 4718592);
    hipLaunchKernelGGL(k_wprepH, dim3(416), dim3(256), 0, stream,
        rw1, wb + WR1, 6, 49, 8, 196, 256, 106496);
    hipLaunchKernelGGL(k_wprepH, dim3(2512), dim3(256), 0, stream,
        rw2, wb + WR2, 196, 25, 200, 128, 128, 643072);
    hipLaunchKernelGGL(k_wprepH, dim3(288), dim3(256), 0, stream,
        rw3, wb + WR3, 128, 9, 128, 64, 64, 73728);

    // ---- backbone (NT=4, BM = 64*MT) ----
    hipLaunchKernelGGL((k_convH<49, 7, 2, 8, 2>), dim3(288, 1, 2), dim3(256), 0, stream,
        imhI, 400, 1280000L, wb + WB1, (const float*)nullptr,
        b1hI, 208, 2768896L, 64, 64, 192, 3, 416, 64, 1.f, 1.f);
    hipLaunchKernelGGL((k_convH<9, 3, 2, 64, 2>), dim3(72, 4, 2), dim3(256), 0, stream,
        b1hI, 208, 2768896L, wb + WB2, (const float*)nullptr,
        b2hI, 112, 3211264L, 256, 256, 96, 1, 576, 256, 1.f, 1.f);
    hipLaunchKernelGGL((k_convH<9, 3, 2, 256, 2>), dim3(18, 8, 2), dim3(256), 0, stream,
        b2hI, 112, 3211264L, wb + WB3, (const float*)nullptr,
        f3hI, 72, 2654208L, 512, 512, 48, 1, 2304, 512, 1.f, 1.f);
    hipLaunchKernelGGL((k_convH<9, 3, 2, 512, 1>), dim3(9, 16, 2), dim3(256), 0, stream,
        f3hI, 72, 2654208L, wb + WB4, (const float*)nullptr,
        f4hI, 48, 2359296L, 1024, 1024, 24, 1, 4608, 1024, 1.f, 1.f);

    // ---- feature extraction ----
    hipLaunchKernelGGL(k_praw, dim3(1, 1024, 12), dim3(256), 0, stream,
        f3hI, f4hI, meta, wsf + PRAW);
    hipLaunchKernelGGL(k_psc, dim3(2, 1024, 36), dim3(256), 0, stream,
        wsf + PRAW, meta, wsf + PSC);
    hipLaunchKernelGGL(k_wsim, dim3(20736, 1, 4), dim3(256), 0, stream,
        wsf + PSC, meta, wsim);
    hipLaunchKernelGGL(k_fill0, dim3(203), dim3(256), 0, stream,
        wsf + SIMRAW, 51840);
    // lvl0: 12 m-bands x 32 ch-blocks x 2 = 768 blocks, LDS 43.7 KB
    hipLaunchKernelGGL((k_simS<3, 48, 72, 512, 21, 65, false>),
        dim3(12, 32, 2), dim3(256), 0, stream,
        f3hI, 2654208L, wsim, wsf + SIMRAW);
    // lvl1: 9 m-bands x 64 ch-blocks x 2 = 1152 blocks, LDS 27.6 KB
    hipLaunchKernelGGL((k_simS<1, 24, 48, 1024, 21, 41, true>),
        dim3(9, 64, 2), dim3(256), 0, stream,
        f4hI, 2359296L, wsim, wsf + SIMRAW);
    hipLaunchKernelGGL(k_sims, dim3(432), dim3(256), 0, stream,
        wsf + SIMRAW, simshI);
    // phase-2 halos (f3h/f4h/PSC/WSIM dead from here)
    hipLaunchKernelGGL(k_halos2, dim3(2400, 4), dim3(256), 0, stream, wsf);

    // ---- count regressor ----
    hipLaunchKernelGGL((k_convH<49, 7, 1, 8, 2>), dim3(18, 4, 6), dim3(256), 0, stream,
        simshI, 64, 32768L, wb + WR1, rb1,
        r1hI, 64, 819200L, 196, 256, 48, 3, 416, 200, 1024.f, INV64);
    hipLaunchKernelGGL(k_up2acH, dim3(5400), dim3(256), 0, stream,
        (const h8*)r1hI, 64, 102400L, (h8*)u1hI, 112, 313600L, 6, 48, 48, 25);
    hipLaunchKernelGGL((k_convH<25, 5, 1, 200, 2>), dim3(72, 2, 6), dim3(256), 0, stream,
        u1hI, 112, 2508800L, wb + WR2, rb2,
        r2h, 96, 1179648L, 128, 128, 96, 2, 5024, 128, 64.f, INV64);
    hipLaunchKernelGGL(k_up2acH, dim3(13824), dim3(256), 0, stream,
        (const h8*)r2h, 96, 147456L, (h8*)u2hI, 208, 692224L, 6, 96, 96, 16);
    hipLaunchKernelGGL((k_convH<9, 3, 1, 128, 2>), dim3(288, 1, 6), dim3(256), 0, stream,
        u2hI, 208, 5537792L, wb + WR3, rb3,
        r3h, 192, 2359296L, 64, 64, 192, 1, 1152, 64, 64.f, INV64);
    hipLaunchKernelGGL(k_final, dim3(1152), dim3(256), 0, stream,
        (const h8*)r3h, rw4, rb4, rw5, rb5, out);
}

// Round 15
// 981.072 us; speedup vs baseline: 1.3542x; 1.0138x over previous
//
#include <hip/hip_runtime.h>
#include <math.h>

typedef _Float16 h8 __attribute__((ext_vector_type(8)));
typedef float f4 __attribute__((ext_vector_type(4)));

// ---------------------------------------------------------------------------
// Workspace layout (float units). All activations NHWC f16 with spatial HALO
// (zero-filled). Scale chain: sims x2^-10 (r1 dsc=1024); regressor acts x1/64
// (consumers dsc=64); k_final x64. All pow2 (exact).
// Conv K-loop runs 64-K batches -> all Kpad are multiples of 64.
// ---------------------------------------------------------------------------
static const size_t OFF_SIMSH = 256;       // (6, 64x64, 8) h halo8
static const size_t OFF_WB    = 98560;     // weight banks, 6909952 h
static const size_t ARENA     = 3553536;
// phase 1
static const size_t IMH  = 3553536;    // (2,400x400,8) h halo8
static const size_t B1H  = 4833536;    // (2,208x208,64) halo8
static const size_t B2H  = 7602432;    // (2,112x112,256) halo8
static const size_t F3H  = 10813696;   // (2,72x72,512) halo12
static const size_t F4H  = 13467904;   // (2,48x48,1024) halo12
static const size_t PRAW = 15827200;   // fp32 2359296
static const size_t PSC  = 18186496;   // fp32 8957952
static const size_t SIMRAW = 27144448; // fp32 51840
static const size_t WSIM = 27196288;   // f16 15925248 h
// phase 2 (reuses arena after k_sims)
static const size_t R1H = 3553536;     // (6,64x64,200) halo8
static const size_t U1H = 6011136;     // (6,112x112,200) halo8
static const size_t R2H = 13537536;    // (6,96x96,128) no halo
static const size_t U2H = 17076480;    // (6,208x208,128) halo8
static const size_t R3H = 33683712;    // (6,192x192,64) no halo

// f16-unit offsets inside WB bank (Kpad mult of 64)
static const size_t WB1 = 0;          // 56kq x 64
static const size_t WB2 = 28672;      // 72 x 256
static const size_t WB3 = 176128;     // 288 x 512
static const size_t WB4 = 1355776;    // 576 x 1024
static const size_t WR1 = 6074368;    // 56 x 256
static const size_t WR2 = 6189056;    // 632 x 128
static const size_t WR3 = 6836224;    // 144 x 64

// ---------------------------------------------------------------------------
__global__ __launch_bounds__(64) void k_meta(const float* __restrict__ tlbrs,
                                             int* __restrict__ meta)
{
    if (threadIdx.x != 0 || blockIdx.x != 0) return;
    const double SC[3] = {1.0, 0.9, 1.1};
    for (int b = 0; b < 2; ++b)
        for (int lvl = 0; lvl < 2; ++lvl) {
            int FH = lvl ? 24 : 48;
            float scaling = lvl ? 16.f : 8.f;
            int base = (b * 2 + lvl) * 32;
            int PH = 0, PW = 0;
            for (int p = 0; p < 3; ++p) {
                const float* t4 = tlbrs + (b * 3 + p) * 4;
                float st = t4[0] / scaling, sl = t4[1] / scaling;
                float sb = t4[2] / scaling, sr = t4[3] / scaling;
                int top  = (int)fmaxf(floorf(st), 0.f);
                int left = (int)fmaxf(floorf(sl), 0.f);
                int bot  = (int)fminf(ceilf(sb) + 1.f, (float)FH);
                int rgt  = (int)fminf(ceilf(sr) + 1.f, (float)FH);
                meta[base + p * 4 + 0] = top;
                meta[base + p * 4 + 1] = left;
                meta[base + p * 4 + 2] = bot;
                meta[base + p * 4 + 3] = rgt;
                PH = max(PH, bot - top);
                PW = max(PW, rgt - left);
            }
            meta[base + 12] = PH;
            meta[base + 13] = PW;
            for (int s = 0; s < 3; ++s) {
                int PHs = (int)ceil((double)PH * SC[s]);
                int PWs = (int)ceil((double)PW * SC[s]);
                if (PHs < 1) PHs = PH;
                if (PWs < 1) PWs = PW;
                meta[base + 14 + s * 2] = PHs;
                meta[base + 15 + s * 2] = PWs;
            }
        }
}

// ---------------------------------------------------------------------------
__device__ __forceinline__ void halo_zero(h8* base, int Hp, int Wp, int halo,
                                          int Cg, int N)
{
    int inner = Hp - 2 * halo;
    int frame = Hp * Wp - inner * inner;
    long total = (long)N * frame * Cg;
    long idx = (long)blockIdx.x * 256 + threadIdx.x;
    if (idx >= total) return;
    int cg = (int)(idx % Cg);
    long r = idx / Cg;
    int f = (int)(r % frame);
    int n = (int)(r / frame);
    int topN = halo * Wp;
    int y, x;
    if (f < topN) { y = f / Wp; x = f % Wp; }
    else if (f < 2 * topN) { int f2 = f - topN; y = Hp - halo + f2 / Wp; x = f2 % Wp; }
    else {
        int f3 = f - 2 * topN;
        int row = f3 / (2 * halo), rr = f3 - row * (2 * halo);
        y = halo + row;
        x = rr < halo ? rr : Wp - 2 * halo + rr;
    }
    h8 z;
#pragma unroll
    for (int j = 0; j < 8; ++j) z[j] = (_Float16)0.f;
    base[((long)n * Hp * Wp + (long)y * Wp + x) * Cg + cg] = z;
}

__global__ __launch_bounds__(256) void k_halos1(float* wsf)
{
    switch (blockIdx.y) {
    case 0: halo_zero((h8*)(wsf + IMH), 400, 400, 8, 1, 2); break;
    case 1: halo_zero((h8*)(wsf + B1H), 208, 208, 8, 8, 2); break;
    case 2: halo_zero((h8*)(wsf + B2H), 112, 112, 8, 32, 2); break;
    case 3: halo_zero((h8*)(wsf + F3H), 72, 72, 12, 64, 2); break;
    default: halo_zero((h8*)(wsf + F4H), 48, 48, 12, 128, 2); break;
    }
}

__global__ __launch_bounds__(256) void k_halos2(float* wsf)
{
    switch (blockIdx.y) {
    case 0: halo_zero((h8*)(wsf + OFF_SIMSH), 64, 64, 8, 1, 6); break;
    case 1: halo_zero((h8*)(wsf + R1H), 64, 64, 8, 25, 6); break;
    case 2: halo_zero((h8*)(wsf + U1H), 112, 112, 8, 25, 6); break;
    default: halo_zero((h8*)(wsf + U2H), 208, 208, 8, 16, 6); break;
    }
}

// ---------------------------------------------------------------------------
__global__ __launch_bounds__(256) void k_im2hwc(const float* __restrict__ img,
    _Float16* __restrict__ o)
{
    int idx = blockIdx.x * 256 + threadIdx.x;
    if (idx >= 2359296) return;
    int c = idx & 7;
    int pix = (idx >> 3) % 147456;
    int b = (idx >> 3) / 147456;
    int y = pix / 384, x = pix - y * 384;
    float v = (c < 3) ? img[((size_t)b * 3 + c) * 147456 + pix] : 0.f;
    o[((size_t)b * 1280000 + ((size_t)(y + 8) * 400 + (x + 8)) * 8) + c] = (_Float16)v;
}

// ---------------------------------------------------------------------------
__global__ __launch_bounds__(256) void k_wprepH(const float* __restrict__ w,
    _Float16* __restrict__ wB, int Cin, int KKt, int Cinp, int Cout, int Coutp,
    int total)
{
    int idx = blockIdx.x * 256 + threadIdx.x;
    if (idx >= total) return;
    int j = idx & 7;
    int co = (idx >> 3) % Coutp;
    int kq = idx / (8 * Coutp);
    int k = kq * 8 + j;
    int tap = k / Cinp, cip = k - tap * Cinp;
    float v = 0.f;
    if (tap < KKt && cip < Cin && co < Cout)
        v = w[((size_t)co * Cin + cip) * KKt + tap];
    wB[idx] = (_Float16)v;
}

// ---------------------------------------------------------------------------
// Halo NHWC implicit-GEMM conv, NT=4 outer product, BM = 64*MT, BN = 64.
// K-loop in 64-K batches (2 steps): 12 loads issued together, 16 MFMAs,
// software-pipelined depth 1 -> ~2 batches of loads in flight. No bounds
// checks (halo + zero-padded wB, Kpad mult of 64).
// ---------------------------------------------------------------------------
template<int KK, int KW, int S, int CINP, int MT>
__global__ __launch_bounds__(256, 3) void k_convH(
    const _Float16* __restrict__ inI, int Winp, long inStride,
    const _Float16* __restrict__ wB, const float* __restrict__ bias,
    _Float16* __restrict__ outI, int Wop, long outStride,
    int Cout, int Coutp, int Wout, int pad, int Kpad, int storeC,
    float dsc, float osc)
{
    const int tid = threadIdx.x;
    const int n_img = blockIdx.z;
    const int m0 = blockIdx.x * (MT * 64);
    const int co0 = blockIdx.y * 64;
    const _Float16* inb = inI + (size_t)n_img * inStride;

    const int wv = tid >> 6, lane = tid & 63;
    const int lq = lane >> 4, lr = lane & 15;

    const _Float16* pb[MT];
#pragma unroll
    for (int mt = 0; mt < MT; ++mt) {
        int m = m0 + (wv * MT + mt) * 16 + lr;
        int y = m / Wout, x = m - y * Wout;
        pb[mt] = inb + ((long)(y * S - pad) * Winp + (x * S - pad)) * CINP;
    }
    const _Float16* wbc = wB + (size_t)(co0 + lr) * 8;

    f4 acc[MT][4];
#pragma unroll
    for (int i = 0; i < MT; ++i)
#pragma unroll
        for (int j = 0; j < 4; ++j) { f4 z = {0.f, 0.f, 0.f, 0.f}; acc[i][j] = z; }

    const int Kbat = Kpad >> 6;     // 64-K batches

    auto load_step = [&](int kb, h8* afX, h8* bfX) {
        int k0 = kb * 32 + lq * 8;
        int tap = k0 / CINP;
        int ci0 = k0 - tap * CINP;
        int dy = tap / KW, dx = tap - dy * KW;
        size_t kq = (size_t)(kb * 4 + lq) * Coutp;
#pragma unroll
        for (int nt = 0; nt < 4; ++nt)
            bfX[nt] = *(const h8*)(wbc + (kq + nt * 16) * 8);
        int doff = (dy * Winp + dx) * CINP + ci0;
#pragma unroll
        for (int mt = 0; mt < MT; ++mt)
            afX[mt] = *(const h8*)(pb[mt] + doff);
    };
    auto mfma_step = [&](h8* afX, h8* bfX) {
#pragma unroll
        for (int mt = 0; mt < MT; ++mt)
#pragma unroll
            for (int nt = 0; nt < 4; ++nt)
                acc[mt][nt] = __builtin_amdgcn_mfma_f32_16x16x32_f16(
                    afX[mt], bfX[nt], acc[mt][nt], 0, 0, 0);
    };
    auto load_batch = [&](int bb, h8 afX[2][MT > 0 ? MT : 1], h8 bfX[2][4]) {
        load_step(2 * bb, afX[0], bfX[0]);
        load_step(2 * bb + 1, afX[1], bfX[1]);
    };
    auto mfma_batch = [&](h8 afX[2][MT > 0 ? MT : 1], h8 bfX[2][4]) {
        mfma_step(afX[0], bfX[0]);
        mfma_step(afX[1], bfX[1]);
    };

    h8 afA[2][MT > 0 ? MT : 1], bfA[2][4], afB[2][MT > 0 ? MT : 1], bfB[2][4];
    load_batch(0, afA, bfA);
    int bb = 0;
    for (; bb + 1 < Kbat; bb += 2) {
        load_batch(bb + 1, afB, bfB);
        mfma_batch(afA, bfA);
        if (bb + 2 < Kbat) load_batch(bb + 2, afA, bfA);
        mfma_batch(afB, bfB);
    }
    if (bb < Kbat) mfma_batch(afA, bfA);

    _Float16* ob = outI + (size_t)n_img * outStride;
#pragma unroll
    for (int nt = 0; nt < 4; ++nt) {
        int co = co0 + nt * 16 + lr;
        if (co >= storeC) continue;
        bool valid = co < Cout;
        float bv = (bias && valid) ? bias[co] : 0.f;
#pragma unroll
        for (int mt = 0; mt < MT; ++mt) {
#pragma unroll
            for (int reg = 0; reg < 4; ++reg) {
                int m = m0 + (wv * MT + mt) * 16 + lq * 4 + reg;
                int y = m / Wout, x = m - y * Wout;
                float v = valid
                    ? fmaxf(fmaf(acc[mt][nt][reg], dsc, bv), 0.f) * osc : 0.f;
                ob[((long)y * Wop + x) * storeC + co] = (_Float16)v;
            }
        }
    }
}

// ---------------------------------------------------------------------------
__global__ __launch_bounds__(256) void k_praw(const _Float16* __restrict__ f3hI,
    const _Float16* __restrict__ f4hI, const int* __restrict__ meta,
    float* __restrict__ praw)
{
    int z = blockIdx.z;
    int p = z % 3, m = z / 3, lvl = m % 2, b = m / 2;
    int c = blockIdx.y;
    int FC = lvl ? 1024 : 512;
    if (c >= FC) return;
    int FHp = lvl ? 48 : 72;
    int fsh = lvl ? 10 : 9;
    const int* mb = meta + m * 32;
    int PH = mb[12], PW = mb[13];
    int oy = threadIdx.x / 16, ox = threadIdx.x % 16;
    if (oy >= PH || ox >= PW) return;
    int top = mb[p * 4 + 0], left = mb[p * 4 + 1];
    int bot = mb[p * 4 + 2], rgt = mb[p * 4 + 3];
    int h = bot - top, w = rgt - left;
    const _Float16* fm = lvl ? (f4hI + (size_t)b * 2359296)
                             : (f3hI + (size_t)b * 2654208);
    float sy = ((oy + 0.5f) * h) / PH - 0.5f;
    sy = fminf(fmaxf(sy, 0.f), (float)(h - 1));
    int y0 = (int)floorf(sy); float ty = sy - y0; int y1 = min(y0 + 1, h - 1);
    float sx = ((ox + 0.5f) * w) / PW - 0.5f;
    sx = fminf(fmaxf(sx, 0.f), (float)(w - 1));
    int x0 = (int)floorf(sx); float tx = sx - x0; int x1 = min(x0 + 1, w - 1);
    float v00 = (float)fm[((size_t)((top + y0) * FHp + (left + x0)) << fsh) + c];
    float v01 = (float)fm[((size_t)((top + y0) * FHp + (left + x1)) << fsh) + c];
    float v10 = (float)fm[((size_t)((top + y1) * FHp + (left + x0)) << fsh) + c];
    float v11 = (float)fm[((size_t)((top + y1) * FHp + (left + x1)) << fsh) + c];
    float v = (1.f - ty) * ((1.f - tx) * v00 + tx * v01)
            +        ty  * ((1.f - tx) * v10 + tx * v11);
    size_t base = (size_t)(b * 1179648 + (lvl ? 393216 : 0)) + ((size_t)p * FC + c) * 256;
    praw[base + oy * 16 + ox] = v;
}

// ---------------------------------------------------------------------------
__global__ __launch_bounds__(256) void k_psc(const float* __restrict__ praw,
    const int* __restrict__ meta, float* __restrict__ psc)
{
    int z = blockIdx.z;
    int p = z % 3, s = (z / 3) % 3, lvl = (z / 9) % 2, b = z / 18;
    int c = blockIdx.y;
    int FC = lvl ? 1024 : 512;
    if (c >= FC) return;
    const int* mb = meta + (b * 2 + lvl) * 32;
    int PH = mb[12], PW = mb[13];
    int PHs = mb[14 + s * 2], PWs = mb[15 + s * 2];
    int idx = blockIdx.x * 256 + threadIdx.x;
    int ys = idx / 18, xs = idx % 18;
    if (ys >= PHs || xs >= PWs) return;
    const float* src = praw + (size_t)(b * 1179648 + (lvl ? 393216 : 0))
                            + ((size_t)p * FC + c) * 256;
    float sy = ((ys + 0.5f) * PH) / PHs - 0.5f;
    sy = fminf(fmaxf(sy, 0.f), (float)(PH - 1));
    int y0 = (int)floorf(sy); float ty = sy - y0; int y1 = min(y0 + 1, PH - 1);
    float sx = ((xs + 0.5f) * PW) / PWs - 0.5f;
    sx = fminf(fmaxf(sx, 0.f), (float)(PW - 1));
    int x0 = (int)floorf(sx); float tx = sx - x0; int x1 = min(x0 + 1, PW - 1);
    float v = (1.f - ty) * ((1.f - tx) * src[y0 * 16 + x0] + tx * src[y0 * 16 + x1])
            +        ty  * ((1.f - tx) * src[y1 * 16 + x0] + tx * src[y1 * 16 + x1]);
    size_t base = (size_t)b * 4478976 + (lvl ? (1492992 + (size_t)s * 995328)
                                             : ((size_t)s * 497664));
    psc[base + ((size_t)p * FC + c) * 324 + ys * 18 + xs] = v;
}

__global__ __launch_bounds__(256) void k_fill0(float* p, int n)
{
    int i = blockIdx.x * 256 + threadIdx.x;
    if (i < n) p[i] = 0.f;
}

// ---------------------------------------------------------------------------
// Sim filter bank, k = (cb, tap, ci) with 16-ch blocks: Wz[kq][n(16)][8] f16.
// ---------------------------------------------------------------------------
__global__ __launch_bounds__(256) void k_wsim(const float* __restrict__ psc,
    const int* __restrict__ meta, _Float16* __restrict__ W)
{
    int z = blockIdx.z;                 // b*2+lvl
    int lvl = z & 1, b = z >> 1;
    int FC = lvl ? 1024 : 512;
    int total = FC * 324 * 16;
    int e = blockIdx.x * 256 + threadIdx.x;
    if (e >= total) return;
    _Float16* Wz = W + (size_t)b * 7962624 + (lvl ? 2654208 : 0);
    int j = e & 7, n = (e >> 3) & 15, kq = e >> 7;
    int k = kq * 8 + j;
    int ci = k & 15;
    int tapcb = k >> 4;
    int tap = tapcb % 324;
    int cb = tapcb / 324;
    int c = cb * 16 + ci;
    int rr = tap / 18, cc = tap - rr * 18;
    float v = 0.f;
    if (n < 9) {
        int s = n / 3, p = n % 3;
        const int* mb = meta + z * 32;
        int PHs = mb[14 + s * 2], PWs = mb[15 + s * 2];
        int ky = rr - (9 - (PHs >> 1));
        int kx = cc - (9 - (PWs >> 1));
        if ((unsigned)ky < (unsigned)PHs && (unsigned)kx < (unsigned)PWs) {
            size_t base = (size_t)b * 4478976 + (lvl ? (1492992 + (size_t)s * 995328)
                                                     : ((size_t)s * 497664));
            v = psc[base + ((size_t)p * FC + c) * 324 + ky * 18 + kx];
        }
    }
    Wz[e] = (_Float16)v;
}

// ---------------------------------------------------------------------------
// Sim GEMM with LDS-staged fm slice (unchanged from r14).
// ---------------------------------------------------------------------------
template<int TW, int FH, int FHP, int FC, int SROWS, int SCOLSU, bool LVL>
__global__ __launch_bounds__(256) void k_simS(
    const _Float16* __restrict__ fI, long fStride,
    const _Float16* __restrict__ Wb, float* __restrict__ simraw)
{
    __shared__ __align__(16) _Float16 As[2 * SROWS * SCOLSU * 8];
    const int M = FH * FH;
    const int PIX = TW * 64;
    const int b = blockIdx.z;
    const int mg = blockIdx.x;
    const int cb = blockIdx.y;
    const _Float16* fm = fI + (size_t)b * fStride;
    const _Float16* Wz = Wb + (size_t)b * 7962624 + (LVL ? 2654208 : 0)
                       + (size_t)cb * 82944;
    const int tid = threadIdx.x;
    const int y0row = (mg * PIX) / FH;

    const int count = 2 * SROWS * SCOLSU;
    for (int idx = tid; idx < count; idx += 256) {
        int half = idx / (SROWS * SCOLSU);
        int rem = idx - half * (SROWS * SCOLSU);
        int row = rem / SCOLSU, col = rem - row * SCOLSU;
        const _Float16* src = fm + ((long)(y0row + row - 9) * FHP + (col - 9)) * FC
                            + cb * 16 + half * 8;
        *(h8*)&As[idx * 8] = *(const h8*)src;
    }
    __syncthreads();

    const int wv = tid >> 6, lane = tid & 63;
    const int lq = lane >> 4, lr = lane & 15;
    int abase[TW];
#pragma unroll
    for (int i = 0; i < TW; ++i) {
        int st = mg * (4 * TW) + wv + 4 * i;
        int m = st * 16 + lr;
        int py = m / FH - y0row, px = m - (m / FH) * FH;
        abase[i] = ((lq & 1) * SROWS + py) * SCOLSU + px;
    }
    const int thalf = lq >> 1;

    f4 acc[TW];
#pragma unroll
    for (int i = 0; i < TW; ++i) { f4 z = {0.f, 0.f, 0.f, 0.f}; acc[i] = z; }

    auto load_step = [&](int step, h8* avX, h8& bfX) {
        int tap = step * 2 + thalf;
        int dy = tap / 18, dx = tap - dy * 18;
        bfX = *(const h8*)(Wz + ((size_t)(step * 4 + lq) * 16 + lr) * 8);
        int doff = dy * SCOLSU + dx;
#pragma unroll
        for (int i = 0; i < TW; ++i)
            avX[i] = *(const h8*)&As[(size_t)(abase[i] + doff) * 8];
    };
    auto mfma_step = [&](h8* avX, h8 bfX) {
#pragma unroll
        for (int i = 0; i < TW; ++i)
            acc[i] = __builtin_amdgcn_mfma_f32_16x16x32_f16(avX[i], bfX, acc[i], 0, 0, 0);
    };

    h8 avA[TW], avB[TW], bfA, bfB;
    load_step(0, avA, bfA);
    int kb = 0;
    for (; kb + 1 < 162; kb += 2) {
        load_step(kb + 1, avB, bfB);
        mfma_step(avA, bfA);
        if (kb + 2 < 162) load_step(kb + 2, avA, bfA);
        mfma_step(avB, bfB);
    }
    if (kb < 162) mfma_step(avA, bfA);

    if (lr < 9) {
        int s = lr / 3, p = lr - s * 3;
        float* base = simraw + (size_t)b * 25920
                    + (LVL ? (20736 + (size_t)s * 1728) : ((size_t)s * 6912))
                    + (size_t)p * M;
#pragma unroll
        for (int i = 0; i < TW; ++i) {
            int st = mg * (4 * TW) + wv + 4 * i;
            int row0 = st * 16 + lq * 4;
#pragma unroll
            for (int r = 0; r < 4; ++r) {
                int m = row0 + r;
                if (m < M) atomicAdd(base + m, acc[i][r]);
            }
        }
    }
}

// ---------------------------------------------------------------------------
__global__ __launch_bounds__(256) void k_sims(const float* __restrict__ simraw,
    _Float16* __restrict__ simshI)
{
    int idx = blockIdx.x * 256 + threadIdx.x;
    if (idx >= 110592) return;
    int scat = idx & 7;
    int rest = idx >> 3;
    int x = rest % 48, y = (rest / 48) % 48;
    int p = (rest / 2304) % 3, b = rest / 6912;
    float v = 0.f;
    if (scat < 6) {
        int lvl = scat / 3, s = scat % 3;
        if (lvl == 0) {
            v = simraw[(size_t)b * 25920 + (size_t)s * 6912 + (size_t)p * 2304 + y * 48 + x];
        } else {
            const float* src = simraw + (size_t)b * 25920 + 20736 + (size_t)s * 1728
                                      + (size_t)p * 576;
            float sy = (y + 0.5f) * 0.5f - 0.5f; sy = fminf(fmaxf(sy, 0.f), 23.f);
            int y0 = (int)floorf(sy); float ty = sy - y0; int y1 = min(y0 + 1, 23);
            float sx = (x + 0.5f) * 0.5f - 0.5f; sx = fminf(fmaxf(sx, 0.f), 23.f);
            int x0 = (int)floorf(sx); float tx = sx - x0; int x1 = min(x0 + 1, 23);
            v = (1.f - ty) * ((1.f - tx) * src[y0 * 24 + x0] + tx * src[y0 * 24 + x1])
              +        ty  * ((1.f - tx) * src[y1 * 24 + x0] + tx * src[y1 * 24 + x1]);
        }
    }
    int n = b * 3 + p;
    simshI[((size_t)n * 32768 + ((size_t)y * 64 + x) * 8) + scat]
        = (_Float16)(v * 0.0009765625f);   // x 2^-10
}

// ---------------------------------------------------------------------------
__global__ __launch_bounds__(256) void k_up2acH(const h8* __restrict__ inI,
    int inWp, long inStride, h8* __restrict__ outI, int outWp, long outStride,
    int N_, int Hin, int Win, int Cg)
{
    int Hout = 2 * Hin, Wout = 2 * Win;
    size_t total = (size_t)N_ * Hout * Wout * Cg;
    size_t idx = (size_t)blockIdx.x * 256 + threadIdx.x;
    if (idx >= total) return;
    int cg = (int)(idx % Cg);
    size_t r = idx / Cg;
    int x = (int)(r % Wout);
    int y = (int)((r / Wout) % Hout);
    int n = (int)(r / ((size_t)Wout * Hout));
    int dh = 2 * Hin - 1, dw = 2 * Win - 1;
    int ay = y * (Hin - 1);
    int y0 = ay / dh; int y1 = min(y0 + 1, Hin - 1);
    float ty = (float)(ay - y0 * dh) / (float)dh;
    int ax = x * (Win - 1);
    int x0 = ax / dw; int x1 = min(x0 + 1, Win - 1);
    float tx = (float)(ax - x0 * dw) / (float)dw;
    const h8* base = inI + (size_t)n * inStride;
    h8 a = base[((size_t)y0 * inWp + x0) * Cg + cg];
    h8 b8 = base[((size_t)y0 * inWp + x1) * Cg + cg];
    h8 c8 = base[((size_t)y1 * inWp + x0) * Cg + cg];
    h8 d8 = base[((size_t)y1 * inWp + x1) * Cg + cg];
    float w00 = (1.f - ty) * (1.f - tx), w01 = (1.f - ty) * tx;
    float w10 = ty * (1.f - tx), w11 = ty * tx;
    h8 o;
#pragma unroll
    for (int j = 0; j < 8; ++j)
        o[j] = (_Float16)(w00 * (float)a[j] + w01 * (float)b8[j]
                        + w10 * (float)c8[j] + w11 * (float)d8[j]);
    outI[(size_t)n * outStride + ((size_t)y * outWp + x) * Cg + cg] = o;
}

// ---------------------------------------------------------------------------
__global__ __launch_bounds__(256) void k_final(const h8* __restrict__ r3h,
    const float* __restrict__ w4, const float* __restrict__ b4,
    const float* __restrict__ w5, const float* __restrict__ b5,
    float* __restrict__ out)
{
    __shared__ float sw4[2048];
    __shared__ float sb4[32];
    __shared__ float sw5[32];
    int tid = threadIdx.x;
    for (int i = tid; i < 2048; i += 256) sw4[i] = w4[i];
    if (tid < 32) { sb4[tid] = b4[tid]; sw5[tid] = w5[tid]; }
    __syncthreads();
    int idx = blockIdx.x * 256 + tid;
    int x = idx % 384, y = (idx / 384) % 384, b = idx / 147456;
    int ay = y * 191; int y0 = ay / 383; int y1 = min(y0 + 1, 191);
    float ty = (float)(ay - y0 * 383) / 383.f;
    int ax = x * 191; int x0 = ax / 383; int x1 = min(x0 + 1, 191);
    float tx = (float)(ax - x0 * 383) / 383.f;
    float w00 = (1.f - ty) * (1.f - tx), w01 = (1.f - ty) * tx;
    float w10 = ty * (1.f - tx), w11 = ty * tx;
    float best = 0.f;
    for (int p = 0; p < 3; ++p) {
        int n = b * 3 + p;
        float acc[32];
#pragma unroll
        for (int co = 0; co < 32; ++co) acc[co] = sb4[co];
        const h8* rb = r3h + (size_t)n * 36864 * 8;
        for (int cg = 0; cg < 8; ++cg) {
            h8 a00 = rb[(size_t)(y0 * 192 + x0) * 8 + cg];
            h8 a01 = rb[(size_t)(y0 * 192 + x1) * 8 + cg];
            h8 a10 = rb[(size_t)(y1 * 192 + x0) * 8 + cg];
            h8 a11 = rb[(size_t)(y1 * 192 + x1) * 8 + cg];
#pragma unroll
            for (int jj = 0; jj < 8; ++jj) {
                float v = (w00 * (float)a00[jj] + w01 * (float)a01[jj]
                         + w10 * (float)a10[jj] + w11 * (float)a11[jj]) * 64.f;
                int ci = cg * 8 + jj;
#pragma unroll
                for (int co = 0; co < 32; ++co)
                    acc[co] = fmaf(sw4[co * 64 + ci], v, acc[co]);
            }
        }
        float s5 = b5[0];
#pragma unroll
        for (int co = 0; co < 32; ++co)
            s5 = fmaf(fmaxf(acc[co], 0.f), sw5[co], s5);
        s5 = fmaxf(s5, 0.f);
        best = fmaxf(best, s5);
    }
    out[idx] = best;
}

// ---------------------------------------------------------------------------
extern "C" void kernel_launch(void* const* d_in, const int* in_sizes, int n_in,
                              void* d_out, int out_size, void* d_ws, size_t ws_size,
                              hipStream_t stream)
{
    (void)in_sizes; (void)n_in; (void)out_size; (void)ws_size;
    const float* images = (const float*)d_in[0];
    const float* tlbrs  = (const float*)d_in[1];
    const float* fw1 = (const float*)d_in[2];
    const float* fw2 = (const float*)d_in[3];
    const float* fw3 = (const float*)d_in[4];
    const float* fw4 = (const float*)d_in[5];
    const float* rw1 = (const float*)d_in[6];
    const float* rb1 = (const float*)d_in[7];
    const float* rw2 = (const float*)d_in[8];
    const float* rb2 = (const float*)d_in[9];
    const float* rw3 = (const float*)d_in[10];
    const float* rb3 = (const float*)d_in[11];
    const float* rw4 = (const float*)d_in[12];
    const float* rb4 = (const float*)d_in[13];
    const float* rw5 = (const float*)d_in[14];
    const float* rb5 = (const float*)d_in[15];
    float* wsf = (float*)d_ws;
    int* meta = (int*)d_ws;
    float* out = (float*)d_out;
    _Float16* wb = (_Float16*)(wsf + OFF_WB);

    // interior pointers (halo offsets)
    _Float16* imhI   = (_Float16*)(wsf + IMH)  + (8 * 400 + 8) * 8;
    _Float16* b1hI   = (_Float16*)(wsf + B1H)  + (8 * 208 + 8) * 64;
    _Float16* b2hI   = (_Float16*)(wsf + B2H)  + (8 * 112 + 8) * 256;
    _Float16* f3hI   = (_Float16*)(wsf + F3H)  + (12 * 72 + 12) * 512;
    _Float16* f4hI   = (_Float16*)(wsf + F4H)  + (12 * 48 + 12) * 1024;
    _Float16* simshI = (_Float16*)(wsf + OFF_SIMSH) + (8 * 64 + 8) * 8;
    _Float16* r1hI   = (_Float16*)(wsf + R1H)  + (8 * 64 + 8) * 200;
    _Float16* u1hI   = (_Float16*)(wsf + U1H)  + (8 * 112 + 8) * 200;
    _Float16* r2h    = (_Float16*)(wsf + R2H);
    _Float16* u2hI   = (_Float16*)(wsf + U2H)  + (8 * 208 + 8) * 128;
    _Float16* r3h    = (_Float16*)(wsf + R3H);
    _Float16* wsim   = (_Float16*)(wsf + WSIM);

    const float INV64 = 1.f / 64.f;

    hipLaunchKernelGGL(k_halos1, dim3(1728, 5), dim3(256), 0, stream, wsf);
    hipLaunchKernelGGL(k_meta, dim3(1), dim3(64), 0, stream, tlbrs, meta);
    hipLaunchKernelGGL(k_im2hwc, dim3(9216), dim3(256), 0, stream, images,
        (_Float16*)(wsf + IMH));

    // ---- weight banks (Kpad mult of 64) ----
    hipLaunchKernelGGL(k_wprepH, dim3(112), dim3(256), 0, stream,
        fw1, wb + WB1, 3, 49, 8, 64, 64, 28672);
    hipLaunchKernelGGL(k_wprepH, dim3(576), dim3(256), 0, stream,
        fw2, wb + WB2, 64, 9, 64, 256, 256, 147456);
    hipLaunchKernelGGL(k_wprepH, dim3(4608), dim3(256), 0, stream,
        fw3, wb + WB3, 256, 9, 256, 512, 512, 1179648);
    hipLaunchKernelGGL(k_wprepH, dim3(18432), dim3(256), 0, stream,
        fw4, wb + WB4, 512, 9, 512, 1024, 1024, 4718592);
    hipLaunchKernelGGL(k_wprepH, dim3(448), dim3(256), 0, stream,
        rw1, wb + WR1, 6, 49, 8, 196, 256, 114688);
    hipLaunchKernelGGL(k_wprepH, dim3(2528), dim3(256), 0, stream,
        rw2, wb + WR2, 196, 25, 200, 128, 128, 647168);
    hipLaunchKernelGGL(k_wprepH, dim3(288), dim3(256), 0, stream,
        rw3, wb + WR3, 128, 9, 128, 64, 64, 73728);

    // ---- backbone (NT=4, BM = 64*MT, 64-K batches) ----
    hipLaunchKernelGGL((k_convH<49, 7, 2, 8, 2>), dim3(288, 1, 2), dim3(256), 0, stream,
        imhI, 400, 1280000L, wb + WB1, (const float*)nullptr,
        b1hI, 208, 2768896L, 64, 64, 192, 3, 448, 64, 1.f, 1.f);
    hipLaunchKernelGGL((k_convH<9, 3, 2, 64, 2>), dim3(72, 4, 2), dim3(256), 0, stream,
        b1hI, 208, 2768896L, wb + WB2, (const float*)nullptr,
        b2hI, 112, 3211264L, 256, 256, 96, 1, 576, 256, 1.f, 1.f);
    hipLaunchKernelGGL((k_convH<9, 3, 2, 256, 2>), dim3(18, 8, 2), dim3(256), 0, stream,
        b2hI, 112, 3211264L, wb + WB3, (const float*)nullptr,
        f3hI, 72, 2654208L, 512, 512, 48, 1, 2304, 512, 1.f, 1.f);
    hipLaunchKernelGGL((k_convH<9, 3, 2, 512, 1>), dim3(9, 16, 2), dim3(256), 0, stream,
        f3hI, 72, 2654208L, wb + WB4, (const float*)nullptr,
        f4hI, 48, 2359296L, 1024, 1024, 24, 1, 4608, 1024, 1.f, 1.f);

    // ---- feature extraction ----
    hipLaunchKernelGGL(k_praw, dim3(1, 1024, 12), dim3(256), 0, stream,
        f3hI, f4hI, meta, wsf + PRAW);
    hipLaunchKernelGGL(k_psc, dim3(2, 1024, 36), dim3(256), 0, stream,
        wsf + PRAW, meta, wsf + PSC);
    hipLaunchKernelGGL(k_wsim, dim3(20736, 1, 4), dim3(256), 0, stream,
        wsf + PSC, meta, wsim);
    hipLaunchKernelGGL(k_fill0, dim3(203), dim3(256), 0, stream,
        wsf + SIMRAW, 51840);
    hipLaunchKernelGGL((k_simS<3, 48, 72, 512, 21, 65, false>),
        dim3(12, 32, 2), dim3(256), 0, stream,
        f3hI, 2654208L, wsim, wsf + SIMRAW);
    hipLaunchKernelGGL((k_simS<1, 24, 48, 1024, 21, 41, true>),
        dim3(9, 64, 2), dim3(256), 0, stream,
        f4hI, 2359296L, wsim, wsf + SIMRAW);
    hipLaunchKernelGGL(k_sims, dim3(432), dim3(256), 0, stream,
        wsf + SIMRAW, simshI);
    hipLaunchKernelGGL(k_halos2, dim3(2400, 4), dim3(256), 0, stream, wsf);

    // ---- count regressor ----
    hipLaunchKernelGGL((k_convH<49, 7, 1, 8, 2>), dim3(18, 4, 6), dim3(256), 0, stream,
        simshI, 64, 32768L, wb + WR1, rb1,
        r1hI, 64, 819200L, 196, 256, 48, 3, 448, 200, 1024.f, INV64);
    hipLaunchKernelGGL(k_up2acH, dim3(5400), dim3(256), 0, stream,
        (const h8*)r1hI, 64, 102400L, (h8*)u1hI, 112, 313600L, 6, 48, 48, 25);
    hipLaunchKernelGGL((k_convH<25, 5, 1, 200, 2>), dim3(72, 2, 6), dim3(256), 0, stream,
        u1hI, 112, 2508800L, wb + WR2, rb2,
        r2h, 96, 1179648L, 128, 128, 96, 2, 5056, 128, 64.f, INV64);
    hipLaunchKernelGGL(k_up2acH, dim3(13824), dim3(256), 0, stream,
        (const h8*)r2h, 96, 147456L, (h8*)u2hI, 208, 692224L, 6, 96, 96, 16);
    hipLaunchKernelGGL((k_convH<9, 3, 1, 128, 2>), dim3(288, 1, 6), dim3(256), 0, stream,
        u2hI, 208, 5537792L, wb + WR3, rb3,
        r3h, 192, 2359296L, 64, 64, 192, 1, 1152, 64, 64.f, INV64);
    hipLaunchKernelGGL(k_final, dim3(1152), dim3(256), 0, stream,
        (const h8*)r3h, rw4, rb4, rw5, rb5, out);
}

// Round 16
// 957.412 us; speedup vs baseline: 1.3876x; 1.0247x over previous
//
#include <hip/hip_runtime.h>
#include <math.h>

typedef _Float16 h8 __attribute__((ext_vector_type(8)));
typedef _Float16 h4 __attribute__((ext_vector_type(4)));
typedef float f4 __attribute__((ext_vector_type(4)));

// ---------------------------------------------------------------------------
// Workspace layout (float units). NHWC f16 + zero halos. Scale chain:
// sims x2^-10 (r1 dsc=1024); regressor acts x1/64 (dsc=64); k_final x64.
// Split-K convs write fp32 partials to dead regions; k_redH reduces.
// ---------------------------------------------------------------------------
static const size_t OFF_SIMSH = 256;
static const size_t OFF_WB    = 98560;     // weight banks, 6909952 h
static const size_t ARENA     = 3553536;
// phase 1
static const size_t IMH  = 3553536;
static const size_t B1H  = 4833536;
static const size_t B2H  = 7602432;
static const size_t F3H  = 10813696;
static const size_t F4H  = 13467904;
static const size_t PRAW = 15827200;   // also conv2/3/4 split-K partials
static const size_t PSC  = 18186496;
static const size_t SIMRAW = 27144448;
static const size_t WSIM = 27196288;
// phase 2
static const size_t R1H = 3553536;
static const size_t U1H = 6011136;
static const size_t R2H = 13537536;
static const size_t U2H = 17076480;    // also r2 split-K partials (before up2)
static const size_t R3H = 33683712;
static const size_t PCONV = PRAW;      // backbone partials
static const size_t PR2   = U2H;       // r2 partials

// f16-unit offsets inside WB bank (Kpad mult of 64)
static const size_t WB1 = 0;
static const size_t WB2 = 28672;
static const size_t WB3 = 176128;
static const size_t WB4 = 1355776;
static const size_t WR1 = 6074368;
static const size_t WR2 = 6189056;
static const size_t WR3 = 6836224;

// ---------------------------------------------------------------------------
__global__ __launch_bounds__(64) void k_meta(const float* __restrict__ tlbrs,
                                             int* __restrict__ meta)
{
    if (threadIdx.x != 0 || blockIdx.x != 0) return;
    const double SC[3] = {1.0, 0.9, 1.1};
    for (int b = 0; b < 2; ++b)
        for (int lvl = 0; lvl < 2; ++lvl) {
            int FH = lvl ? 24 : 48;
            float scaling = lvl ? 16.f : 8.f;
            int base = (b * 2 + lvl) * 32;
            int PH = 0, PW = 0;
            for (int p = 0; p < 3; ++p) {
                const float* t4 = tlbrs + (b * 3 + p) * 4;
                float st = t4[0] / scaling, sl = t4[1] / scaling;
                float sb = t4[2] / scaling, sr = t4[3] / scaling;
                int top  = (int)fmaxf(floorf(st), 0.f);
                int left = (int)fmaxf(floorf(sl), 0.f);
                int bot  = (int)fminf(ceilf(sb) + 1.f, (float)FH);
                int rgt  = (int)fminf(ceilf(sr) + 1.f, (float)FH);
                meta[base + p * 4 + 0] = top;
                meta[base + p * 4 + 1] = left;
                meta[base + p * 4 + 2] = bot;
                meta[base + p * 4 + 3] = rgt;
                PH = max(PH, bot - top);
                PW = max(PW, rgt - left);
            }
            meta[base + 12] = PH;
            meta[base + 13] = PW;
            for (int s = 0; s < 3; ++s) {
                int PHs = (int)ceil((double)PH * SC[s]);
                int PWs = (int)ceil((double)PW * SC[s]);
                if (PHs < 1) PHs = PH;
                if (PWs < 1) PWs = PW;
                meta[base + 14 + s * 2] = PHs;
                meta[base + 15 + s * 2] = PWs;
            }
        }
}

// ---------------------------------------------------------------------------
__device__ __forceinline__ void halo_zero(h8* base, int Hp, int Wp, int halo,
                                          int Cg, int N)
{
    int inner = Hp - 2 * halo;
    int frame = Hp * Wp - inner * inner;
    long total = (long)N * frame * Cg;
    long idx = (long)blockIdx.x * 256 + threadIdx.x;
    if (idx >= total) return;
    int cg = (int)(idx % Cg);
    long r = idx / Cg;
    int f = (int)(r % frame);
    int n = (int)(r / frame);
    int topN = halo * Wp;
    int y, x;
    if (f < topN) { y = f / Wp; x = f % Wp; }
    else if (f < 2 * topN) { int f2 = f - topN; y = Hp - halo + f2 / Wp; x = f2 % Wp; }
    else {
        int f3 = f - 2 * topN;
        int row = f3 / (2 * halo), rr = f3 - row * (2 * halo);
        y = halo + row;
        x = rr < halo ? rr : Wp - 2 * halo + rr;
    }
    h8 z;
#pragma unroll
    for (int j = 0; j < 8; ++j) z[j] = (_Float16)0.f;
    base[((long)n * Hp * Wp + (long)y * Wp + x) * Cg + cg] = z;
}

__global__ __launch_bounds__(256) void k_halos1(float* wsf)
{
    switch (blockIdx.y) {
    case 0: halo_zero((h8*)(wsf + IMH), 400, 400, 8, 1, 2); break;
    case 1: halo_zero((h8*)(wsf + B1H), 208, 208, 8, 8, 2); break;
    case 2: halo_zero((h8*)(wsf + B2H), 112, 112, 8, 32, 2); break;
    case 3: halo_zero((h8*)(wsf + F3H), 72, 72, 12, 64, 2); break;
    default: halo_zero((h8*)(wsf + F4H), 48, 48, 12, 128, 2); break;
    }
}

__global__ __launch_bounds__(256) void k_halos2a(float* wsf)
{
    switch (blockIdx.y) {
    case 0: halo_zero((h8*)(wsf + OFF_SIMSH), 64, 64, 8, 1, 6); break;
    case 1: halo_zero((h8*)(wsf + R1H), 64, 64, 8, 25, 6); break;
    default: halo_zero((h8*)(wsf + U1H), 112, 112, 8, 25, 6); break;
    }
}

__global__ __launch_bounds__(256) void k_halos2b(float* wsf)
{
    halo_zero((h8*)(wsf + U2H), 208, 208, 8, 16, 6);
}

// ---------------------------------------------------------------------------
__global__ __launch_bounds__(256) void k_im2hwc(const float* __restrict__ img,
    _Float16* __restrict__ o)
{
    int idx = blockIdx.x * 256 + threadIdx.x;
    if (idx >= 2359296) return;
    int c = idx & 7;
    int pix = (idx >> 3) % 147456;
    int b = (idx >> 3) / 147456;
    int y = pix / 384, x = pix - y * 384;
    float v = (c < 3) ? img[((size_t)b * 3 + c) * 147456 + pix] : 0.f;
    o[((size_t)b * 1280000 + ((size_t)(y + 8) * 400 + (x + 8)) * 8) + c] = (_Float16)v;
}

// ---------------------------------------------------------------------------
__global__ __launch_bounds__(256) void k_wprepH(const float* __restrict__ w,
    _Float16* __restrict__ wB, int Cin, int KKt, int Cinp, int Cout, int Coutp,
    int total)
{
    int idx = blockIdx.x * 256 + threadIdx.x;
    if (idx >= total) return;
    int j = idx & 7;
    int co = (idx >> 3) % Coutp;
    int kq = idx / (8 * Coutp);
    int k = kq * 8 + j;
    int tap = k / Cinp, cip = k - tap * Cinp;
    float v = 0.f;
    if (tap < KKt && cip < Cin && co < Cout)
        v = w[((size_t)co * Cin + cip) * KKt + tap];
    wB[idx] = (_Float16)v;
}

// ---------------------------------------------------------------------------
// Halo NHWC implicit-GEMM conv, NT=4, BM = 64*MT, 64-K batches, depth-1 SW
// pipeline. Optional split-K: grid.y = coBlocks*KS; chunk writes raw fp32
// partials (reduced later by k_redH). No bounds checks (halo + zero-pad wB).
// ---------------------------------------------------------------------------
template<int KK, int KW, int S, int CINP, int MT>
__global__ __launch_bounds__(256, 3) void k_convH(
    const _Float16* __restrict__ inI, int Winp, long inStride,
    const _Float16* __restrict__ wB, const float* __restrict__ bias,
    _Float16* __restrict__ outI, int Wop, long outStride,
    int Cout, int Coutp, int Wout, int pad, int Kpad, int storeC,
    float dsc, float osc, int coBlocks, int kbatPer, float* partial)
{
    const int tid = threadIdx.x;
    const int n_img = blockIdx.z;
    const int m0 = blockIdx.x * (MT * 64);
    const int ks  = blockIdx.y / coBlocks;
    const int co0 = (blockIdx.y - ks * coBlocks) * 64;
    const _Float16* inb = inI + (size_t)n_img * inStride;

    const int wv = tid >> 6, lane = tid & 63;
    const int lq = lane >> 4, lr = lane & 15;

    const _Float16* pb[MT];
#pragma unroll
    for (int mt = 0; mt < MT; ++mt) {
        int m = m0 + (wv * MT + mt) * 16 + lr;
        int y = m / Wout, x = m - y * Wout;
        pb[mt] = inb + ((long)(y * S - pad) * Winp + (x * S - pad)) * CINP;
    }
    const _Float16* wbc = wB + (size_t)(co0 + lr) * 8;

    f4 acc[MT][4];
#pragma unroll
    for (int i = 0; i < MT; ++i)
#pragma unroll
        for (int j = 0; j < 4; ++j) { f4 z = {0.f, 0.f, 0.f, 0.f}; acc[i][j] = z; }

    const int Kbat = Kpad >> 6;
    const int bb0 = ks * kbatPer;
    const int bb1 = min(Kbat, bb0 + kbatPer);

    auto load_step = [&](int kb, h8* afX, h8* bfX) {
        int k0 = kb * 32 + lq * 8;
        int tap = k0 / CINP;
        int ci0 = k0 - tap * CINP;
        int dy = tap / KW, dx = tap - dy * KW;
        size_t kq = (size_t)(kb * 4 + lq) * Coutp;
#pragma unroll
        for (int nt = 0; nt < 4; ++nt)
            bfX[nt] = *(const h8*)(wbc + (kq + nt * 16) * 8);
        int doff = (dy * Winp + dx) * CINP + ci0;
#pragma unroll
        for (int mt = 0; mt < MT; ++mt)
            afX[mt] = *(const h8*)(pb[mt] + doff);
    };
    auto mfma_step = [&](h8* afX, h8* bfX) {
#pragma unroll
        for (int mt = 0; mt < MT; ++mt)
#pragma unroll
            for (int nt = 0; nt < 4; ++nt)
                acc[mt][nt] = __builtin_amdgcn_mfma_f32_16x16x32_f16(
                    afX[mt], bfX[nt], acc[mt][nt], 0, 0, 0);
    };
    auto load_batch = [&](int bb, h8 afX[2][MT > 0 ? MT : 1], h8 bfX[2][4]) {
        load_step(2 * bb, afX[0], bfX[0]);
        load_step(2 * bb + 1, afX[1], bfX[1]);
    };
    auto mfma_batch = [&](h8 afX[2][MT > 0 ? MT : 1], h8 bfX[2][4]) {
        mfma_step(afX[0], bfX[0]);
        mfma_step(afX[1], bfX[1]);
    };

    h8 afA[2][MT > 0 ? MT : 1], bfA[2][4], afB[2][MT > 0 ? MT : 1], bfB[2][4];
    load_batch(bb0, afA, bfA);
    int bb = bb0;
    for (; bb + 1 < bb1; bb += 2) {
        load_batch(bb + 1, afB, bfB);
        mfma_batch(afA, bfA);
        if (bb + 2 < bb1) load_batch(bb + 2, afA, bfA);
        mfma_batch(afB, bfB);
    }
    if (bb < bb1) mfma_batch(afA, bfA);

    if (partial) {
        // raw fp32 partial: [ks][n][m][co], C = coBlocks*64
        const int Mtot = gridDim.x * (MT * 64);
        const int C = coBlocks * 64;
        const size_t chunk = (size_t)gridDim.z * Mtot * C;
        float* pp = partial + (size_t)ks * chunk + (size_t)n_img * Mtot * C;
#pragma unroll
        for (int nt = 0; nt < 4; ++nt) {
            int co = co0 + nt * 16 + lr;
#pragma unroll
            for (int mt = 0; mt < MT; ++mt) {
#pragma unroll
                for (int reg = 0; reg < 4; ++reg) {
                    int m = m0 + (wv * MT + mt) * 16 + lq * 4 + reg;
                    pp[(size_t)m * C + co] = acc[mt][nt][reg];
                }
            }
        }
        return;
    }

    _Float16* ob = outI + (size_t)n_img * outStride;
#pragma unroll
    for (int nt = 0; nt < 4; ++nt) {
        int co = co0 + nt * 16 + lr;
        if (co >= storeC) continue;
        bool valid = co < Cout;
        float bv = (bias && valid) ? bias[co] : 0.f;
#pragma unroll
        for (int mt = 0; mt < MT; ++mt) {
#pragma unroll
            for (int reg = 0; reg < 4; ++reg) {
                int m = m0 + (wv * MT + mt) * 16 + lq * 4 + reg;
                int y = m / Wout, x = m - y * Wout;
                float v = valid
                    ? fmaxf(fmaf(acc[mt][nt][reg], dsc, bv), 0.f) * osc : 0.f;
                ob[((long)y * Wop + x) * storeC + co] = (_Float16)v;
            }
        }
    }
}

// ---------------------------------------------------------------------------
// Split-K reduce: sum KS fp32 partials, apply bias+relu+scales, emit f16 NHWC
// (halo-strided). 4 channels per thread (C mult of 4; Cout == C).
// ---------------------------------------------------------------------------
__global__ __launch_bounds__(256) void k_redH(const float* __restrict__ partial,
    long chunk, int KS, const float* __restrict__ bias,
    _Float16* __restrict__ outI, int Wop, long outStride, int Wout,
    int C, int M, int N, float dsc, float osc)
{
    long idx4 = (long)blockIdx.x * 256 + threadIdx.x;
    long total4 = (long)N * M * C / 4;
    if (idx4 >= total4) return;
    long e = idx4 * 4;
    int co = (int)(e % C);
    long r = e / C;
    int m = (int)(r % M);
    int n = (int)(r / M);
    f4 s = *(const f4*)(partial + e);
    for (int ks = 1; ks < KS; ++ks) {
        f4 t = *(const f4*)(partial + (size_t)ks * chunk + e);
        s += t;
    }
    h4 o;
#pragma unroll
    for (int j = 0; j < 4; ++j) {
        float bv = bias ? bias[co + j] : 0.f;
        o[j] = (_Float16)(fmaxf(fmaf(s[j], dsc, bv), 0.f) * osc);
    }
    int y = m / Wout, x = m - y * Wout;
    *(h4*)&outI[(size_t)n * outStride + ((size_t)y * Wop + x) * C + co] = o;
}

// ---------------------------------------------------------------------------
__global__ __launch_bounds__(256) void k_praw(const _Float16* __restrict__ f3hI,
    const _Float16* __restrict__ f4hI, const int* __restrict__ meta,
    float* __restrict__ praw)
{
    int z = blockIdx.z;
    int p = z % 3, m = z / 3, lvl = m % 2, b = m / 2;
    int c = blockIdx.y;
    int FC = lvl ? 1024 : 512;
    if (c >= FC) return;
    int FHp = lvl ? 48 : 72;
    int fsh = lvl ? 10 : 9;
    const int* mb = meta + m * 32;
    int PH = mb[12], PW = mb[13];
    int oy = threadIdx.x / 16, ox = threadIdx.x % 16;
    if (oy >= PH || ox >= PW) return;
    int top = mb[p * 4 + 0], left = mb[p * 4 + 1];
    int bot = mb[p * 4 + 2], rgt = mb[p * 4 + 3];
    int h = bot - top, w = rgt - left;
    const _Float16* fm = lvl ? (f4hI + (size_t)b * 2359296)
                             : (f3hI + (size_t)b * 2654208);
    float sy = ((oy + 0.5f) * h) / PH - 0.5f;
    sy = fminf(fmaxf(sy, 0.f), (float)(h - 1));
    int y0 = (int)floorf(sy); float ty = sy - y0; int y1 = min(y0 + 1, h - 1);
    float sx = ((ox + 0.5f) * w) / PW - 0.5f;
    sx = fminf(fmaxf(sx, 0.f), (float)(w - 1));
    int x0 = (int)floorf(sx); float tx = sx - x0; int x1 = min(x0 + 1, w - 1);
    float v00 = (float)fm[((size_t)((top + y0) * FHp + (left + x0)) << fsh) + c];
    float v01 = (float)fm[((size_t)((top + y0) * FHp + (left + x1)) << fsh) + c];
    float v10 = (float)fm[((size_t)((top + y1) * FHp + (left + x0)) << fsh) + c];
    float v11 = (float)fm[((size_t)((top + y1) * FHp + (left + x1)) << fsh) + c];
    float v = (1.f - ty) * ((1.f - tx) * v00 + tx * v01)
            +        ty  * ((1.f - tx) * v10 + tx * v11);
    size_t base = (size_t)(b * 1179648 + (lvl ? 393216 : 0)) + ((size_t)p * FC + c) * 256;
    praw[base + oy * 16 + ox] = v;
}

// ---------------------------------------------------------------------------
__global__ __launch_bounds__(256) void k_psc(const float* __restrict__ praw,
    const int* __restrict__ meta, float* __restrict__ psc)
{
    int z = blockIdx.z;
    int p = z % 3, s = (z / 3) % 3, lvl = (z / 9) % 2, b = z / 18;
    int c = blockIdx.y;
    int FC = lvl ? 1024 : 512;
    if (c >= FC) return;
    const int* mb = meta + (b * 2 + lvl) * 32;
    int PH = mb[12], PW = mb[13];
    int PHs = mb[14 + s * 2], PWs = mb[15 + s * 2];
    int idx = blockIdx.x * 256 + threadIdx.x;
    int ys = idx / 18, xs = idx % 18;
    if (ys >= PHs || xs >= PWs) return;
    const float* src = praw + (size_t)(b * 1179648 + (lvl ? 393216 : 0))
                            + ((size_t)p * FC + c) * 256;
    float sy = ((ys + 0.5f) * PH) / PHs - 0.5f;
    sy = fminf(fmaxf(sy, 0.f), (float)(PH - 1));
    int y0 = (int)floorf(sy); float ty = sy - y0; int y1 = min(y0 + 1, PH - 1);
    float sx = ((xs + 0.5f) * PW) / PWs - 0.5f;
    sx = fminf(fmaxf(sx, 0.f), (float)(PW - 1));
    int x0 = (int)floorf(sx); float tx = sx - x0; int x1 = min(x0 + 1, PW - 1);
    float v = (1.f - ty) * ((1.f - tx) * src[y0 * 16 + x0] + tx * src[y0 * 16 + x1])
            +        ty  * ((1.f - tx) * src[y1 * 16 + x0] + tx * src[y1 * 16 + x1]);
    size_t base = (size_t)b * 4478976 + (lvl ? (1492992 + (size_t)s * 995328)
                                             : ((size_t)s * 497664));
    psc[base + ((size_t)p * FC + c) * 324 + ys * 18 + xs] = v;
}

__global__ __launch_bounds__(256) void k_fill0(float* p, int n)
{
    int i = blockIdx.x * 256 + threadIdx.x;
    if (i < n) p[i] = 0.f;
}

// ---------------------------------------------------------------------------
// Sim filter bank, k = (cb, tap, ci) with 16-ch blocks: Wz[kq][n(16)][8] f16.
// ---------------------------------------------------------------------------
__global__ __launch_bounds__(256) void k_wsim(const float* __restrict__ psc,
    const int* __restrict__ meta, _Float16* __restrict__ W)
{
    int z = blockIdx.z;                 // b*2+lvl
    int lvl = z & 1, b = z >> 1;
    int FC = lvl ? 1024 : 512;
    int total = FC * 324 * 16;
    int e = blockIdx.x * 256 + threadIdx.x;
    if (e >= total) return;
    _Float16* Wz = W + (size_t)b * 7962624 + (lvl ? 2654208 : 0);
    int j = e & 7, n = (e >> 3) & 15, kq = e >> 7;
    int k = kq * 8 + j;
    int ci = k & 15;
    int tapcb = k >> 4;
    int tap = tapcb % 324;
    int cb = tapcb / 324;
    int c = cb * 16 + ci;
    int rr = tap / 18, cc = tap - rr * 18;
    float v = 0.f;
    if (n < 9) {
        int s = n / 3, p = n % 3;
        const int* mb = meta + z * 32;
        int PHs = mb[14 + s * 2], PWs = mb[15 + s * 2];
        int ky = rr - (9 - (PHs >> 1));
        int kx = cc - (9 - (PWs >> 1));
        if ((unsigned)ky < (unsigned)PHs && (unsigned)kx < (unsigned)PWs) {
            size_t base = (size_t)b * 4478976 + (lvl ? (1492992 + (size_t)s * 995328)
                                                     : ((size_t)s * 497664));
            v = psc[base + ((size_t)p * FC + c) * 324 + ky * 18 + kx];
        }
    }
    Wz[e] = (_Float16)v;
}

// ---------------------------------------------------------------------------
// Sim GEMM with LDS-staged fm slice.
// ---------------------------------------------------------------------------
template<int TW, int FH, int FHP, int FC, int SROWS, int SCOLSU, bool LVL>
__global__ __launch_bounds__(256) void k_simS(
    const _Float16* __restrict__ fI, long fStride,
    const _Float16* __restrict__ Wb, float* __restrict__ simraw)
{
    __shared__ __align__(16) _Float16 As[2 * SROWS * SCOLSU * 8];
    const int M = FH * FH;
    const int PIX = TW * 64;
    const int b = blockIdx.z;
    const int mg = blockIdx.x;
    const int cb = blockIdx.y;
    const _Float16* fm = fI + (size_t)b * fStride;
    const _Float16* Wz = Wb + (size_t)b * 7962624 + (LVL ? 2654208 : 0)
                       + (size_t)cb * 82944;
    const int tid = threadIdx.x;
    const int y0row = (mg * PIX) / FH;

    const int count = 2 * SROWS * SCOLSU;
    for (int idx = tid; idx < count; idx += 256) {
        int half = idx / (SROWS * SCOLSU);
        int rem = idx - half * (SROWS * SCOLSU);
        int row = rem / SCOLSU, col = rem - row * SCOLSU;
        const _Float16* src = fm + ((long)(y0row + row - 9) * FHP + (col - 9)) * FC
                            + cb * 16 + half * 8;
        *(h8*)&As[idx * 8] = *(const h8*)src;
    }
    __syncthreads();

    const int wv = tid >> 6, lane = tid & 63;
    const int lq = lane >> 4, lr = lane & 15;
    int abase[TW];
#pragma unroll
    for (int i = 0; i < TW; ++i) {
        int st = mg * (4 * TW) + wv + 4 * i;
        int m = st * 16 + lr;
        int py = m / FH - y0row, px = m - (m / FH) * FH;
        abase[i] = ((lq & 1) * SROWS + py) * SCOLSU + px;
    }
    const int thalf = lq >> 1;

    f4 acc[TW];
#pragma unroll
    for (int i = 0; i < TW; ++i) { f4 z = {0.f, 0.f, 0.f, 0.f}; acc[i] = z; }

    auto load_step = [&](int step, h8* avX, h8& bfX) {
        int tap = step * 2 + thalf;
        int dy = tap / 18, dx = tap - dy * 18;
        bfX = *(const h8*)(Wz + ((size_t)(step * 4 + lq) * 16 + lr) * 8);
        int doff = dy * SCOLSU + dx;
#pragma unroll
        for (int i = 0; i < TW; ++i)
            avX[i] = *(const h8*)&As[(size_t)(abase[i] + doff) * 8];
    };
    auto mfma_step = [&](h8* avX, h8 bfX) {
#pragma unroll
        for (int i = 0; i < TW; ++i)
            acc[i] = __builtin_amdgcn_mfma_f32_16x16x32_f16(avX[i], bfX, acc[i], 0, 0, 0);
    };

    h8 avA[TW], avB[TW], bfA, bfB;
    load_step(0, avA, bfA);
    int kb = 0;
    for (; kb + 1 < 162; kb += 2) {
        load_step(kb + 1, avB, bfB);
        mfma_step(avA, bfA);
        if (kb + 2 < 162) load_step(kb + 2, avA, bfA);
        mfma_step(avB, bfB);
    }
    if (kb < 162) mfma_step(avA, bfA);

    if (lr < 9) {
        int s = lr / 3, p = lr - s * 3;
        float* base = simraw + (size_t)b * 25920
                    + (LVL ? (20736 + (size_t)s * 1728) : ((size_t)s * 6912))
                    + (size_t)p * M;
#pragma unroll
        for (int i = 0; i < TW; ++i) {
            int st = mg * (4 * TW) + wv + 4 * i;
            int row0 = st * 16 + lq * 4;
#pragma unroll
            for (int r = 0; r < 4; ++r) {
                int m = row0 + r;
                if (m < M) atomicAdd(base + m, acc[i][r]);
            }
        }
    }
}

// ---------------------------------------------------------------------------
__global__ __launch_bounds__(256) void k_sims(const float* __restrict__ simraw,
    _Float16* __restrict__ simshI)
{
    int idx = blockIdx.x * 256 + threadIdx.x;
    if (idx >= 110592) return;
    int scat = idx & 7;
    int rest = idx >> 3;
    int x = rest % 48, y = (rest / 48) % 48;
    int p = (rest / 2304) % 3, b = rest / 6912;
    float v = 0.f;
    if (scat < 6) {
        int lvl = scat / 3, s = scat % 3;
        if (lvl == 0) {
            v = simraw[(size_t)b * 25920 + (size_t)s * 6912 + (size_t)p * 2304 + y * 48 + x];
        } else {
            const float* src = simraw + (size_t)b * 25920 + 20736 + (size_t)s * 1728
                                      + (size_t)p * 576;
            float sy = (y + 0.5f) * 0.5f - 0.5f; sy = fminf(fmaxf(sy, 0.f), 23.f);
            int y0 = (int)floorf(sy); float ty = sy - y0; int y1 = min(y0 + 1, 23);
            float sx = (x + 0.5f) * 0.5f - 0.5f; sx = fminf(fmaxf(sx, 0.f), 23.f);
            int x0 = (int)floorf(sx); float tx = sx - x0; int x1 = min(x0 + 1, 23);
            v = (1.f - ty) * ((1.f - tx) * src[y0 * 24 + x0] + tx * src[y0 * 24 + x1])
              +        ty  * ((1.f - tx) * src[y1 * 24 + x0] + tx * src[y1 * 24 + x1]);
        }
    }
    int n = b * 3 + p;
    simshI[((size_t)n * 32768 + ((size_t)y * 64 + x) * 8) + scat]
        = (_Float16)(v * 0.0009765625f);   // x 2^-10
}

// ---------------------------------------------------------------------------
__global__ __launch_bounds__(256) void k_up2acH(const h8* __restrict__ inI,
    int inWp, long inStride, h8* __restrict__ outI, int outWp, long outStride,
    int N_, int Hin, int Win, int Cg)
{
    int Hout = 2 * Hin, Wout = 2 * Win;
    size_t total = (size_t)N_ * Hout * Wout * Cg;
    size_t idx = (size_t)blockIdx.x * 256 + threadIdx.x;
    if (idx >= total) return;
    int cg = (int)(idx % Cg);
    size_t r = idx / Cg;
    int x = (int)(r % Wout);
    int y = (int)((r / Wout) % Hout);
    int n = (int)(r / ((size_t)Wout * Hout));
    int dh = 2 * Hin - 1, dw = 2 * Win - 1;
    int ay = y * (Hin - 1);
    int y0 = ay / dh; int y1 = min(y0 + 1, Hin - 1);
    float ty = (float)(ay - y0 * dh) / (float)dh;
    int ax = x * (Win - 1);
    int x0 = ax / dw; int x1 = min(x0 + 1, Win - 1);
    float tx = (float)(ax - x0 * dw) / (float)dw;
    const h8* base = inI + (size_t)n * inStride;
    h8 a = base[((size_t)y0 * inWp + x0) * Cg + cg];
    h8 b8 = base[((size_t)y0 * inWp + x1) * Cg + cg];
    h8 c8 = base[((size_t)y1 * inWp + x0) * Cg + cg];
    h8 d8 = base[((size_t)y1 * inWp + x1) * Cg + cg];
    float w00 = (1.f - ty) * (1.f - tx), w01 = (1.f - ty) * tx;
    float w10 = ty * (1.f - tx), w11 = ty * tx;
    h8 o;
#pragma unroll
    for (int j = 0; j < 8; ++j)
        o[j] = (_Float16)(w00 * (float)a[j] + w01 * (float)b8[j]
                        + w10 * (float)c8[j] + w11 * (float)d8[j]);
    outI[(size_t)n * outStride + ((size_t)y * outWp + x) * Cg + cg] = o;
}

// ---------------------------------------------------------------------------
__global__ __launch_bounds__(256) void k_final(const h8* __restrict__ r3h,
    const float* __restrict__ w4, const float* __restrict__ b4,
    const float* __restrict__ w5, const float* __restrict__ b5,
    float* __restrict__ out)
{
    __shared__ float sw4[2048];
    __shared__ float sb4[32];
    __shared__ float sw5[32];
    int tid = threadIdx.x;
    for (int i = tid; i < 2048; i += 256) sw4[i] = w4[i];
    if (tid < 32) { sb4[tid] = b4[tid]; sw5[tid] = w5[tid]; }
    __syncthreads();
    int idx = blockIdx.x * 256 + tid;
    int x = idx % 384, y = (idx / 384) % 384, b = idx / 147456;
    int ay = y * 191; int y0 = ay / 383; int y1 = min(y0 + 1, 191);
    float ty = (float)(ay - y0 * 383) / 383.f;
    int ax = x * 191; int x0 = ax / 383; int x1 = min(x0 + 1, 191);
    float tx = (float)(ax - x0 * 383) / 383.f;
    float w00 = (1.f - ty) * (1.f - tx), w01 = (1.f - ty) * tx;
    float w10 = ty * (1.f - tx), w11 = ty * tx;
    float best = 0.f;
    for (int p = 0; p < 3; ++p) {
        int n = b * 3 + p;
        float acc[32];
#pragma unroll
        for (int co = 0; co < 32; ++co) acc[co] = sb4[co];
        const h8* rb = r3h + (size_t)n * 36864 * 8;
        for (int cg = 0; cg < 8; ++cg) {
            h8 a00 = rb[(size_t)(y0 * 192 + x0) * 8 + cg];
            h8 a01 = rb[(size_t)(y0 * 192 + x1) * 8 + cg];
            h8 a10 = rb[(size_t)(y1 * 192 + x0) * 8 + cg];
            h8 a11 = rb[(size_t)(y1 * 192 + x1) * 8 + cg];
#pragma unroll
            for (int jj = 0; jj < 8; ++jj) {
                float v = (w00 * (float)a00[jj] + w01 * (float)a01[jj]
                         + w10 * (float)a10[jj] + w11 * (float)a11[jj]) * 64.f;
                int ci = cg * 8 + jj;
#pragma unroll
                for (int co = 0; co < 32; ++co)
                    acc[co] = fmaf(sw4[co * 64 + ci], v, acc[co]);
            }
        }
        float s5 = b5[0];
#pragma unroll
        for (int co = 0; co < 32; ++co)
            s5 = fmaf(fmaxf(acc[co], 0.f), sw5[co], s5);
        s5 = fmaxf(s5, 0.f);
        best = fmaxf(best, s5);
    }
    out[idx] = best;
}

// ---------------------------------------------------------------------------
extern "C" void kernel_launch(void* const* d_in, const int* in_sizes, int n_in,
                              void* d_out, int out_size, void* d_ws, size_t ws_size,
                              hipStream_t stream)
{
    (void)in_sizes; (void)n_in; (void)out_size; (void)ws_size;
    const float* images = (const float*)d_in[0];
    const float* tlbrs  = (const float*)d_in[1];
    const float* fw1 = (const float*)d_in[2];
    const float* fw2 = (const float*)d_in[3];
    const float* fw3 = (const float*)d_in[4];
    const float* fw4 = (const float*)d_in[5];
    const float* rw1 = (const float*)d_in[6];
    const float* rb1 = (const float*)d_in[7];
    const float* rw2 = (const float*)d_in[8];
    const float* rb2 = (const float*)d_in[9];
    const float* rw3 = (const float*)d_in[10];
    const float* rb3 = (const float*)d_in[11];
    const float* rw4 = (const float*)d_in[12];
    const float* rb4 = (const float*)d_in[13];
    const float* rw5 = (const float*)d_in[14];
    const float* rb5 = (const float*)d_in[15];
    float* wsf = (float*)d_ws;
    int* meta = (int*)d_ws;
    float* out = (float*)d_out;
    _Float16* wb = (_Float16*)(wsf + OFF_WB);

    // interior pointers (halo offsets)
    _Float16* imhI   = (_Float16*)(wsf + IMH)  + (8 * 400 + 8) * 8;
    _Float16* b1hI   = (_Float16*)(wsf + B1H)  + (8 * 208 + 8) * 64;
    _Float16* b2hI   = (_Float16*)(wsf + B2H)  + (8 * 112 + 8) * 256;
    _Float16* f3hI   = (_Float16*)(wsf + F3H)  + (12 * 72 + 12) * 512;
    _Float16* f4hI   = (_Float16*)(wsf + F4H)  + (12 * 48 + 12) * 1024;
    _Float16* simshI = (_Float16*)(wsf + OFF_SIMSH) + (8 * 64 + 8) * 8;
    _Float16* r1hI   = (_Float16*)(wsf + R1H)  + (8 * 64 + 8) * 200;
    _Float16* u1hI   = (_Float16*)(wsf + U1H)  + (8 * 112 + 8) * 200;
    _Float16* r2h    = (_Float16*)(wsf + R2H);
    _Float16* u2hI   = (_Float16*)(wsf + U2H)  + (8 * 208 + 8) * 128;
    _Float16* r3h    = (_Float16*)(wsf + R3H);
    _Float16* wsim   = (_Float16*)(wsf + WSIM);
    float* pconv = wsf + PCONV;
    float* pr2   = wsf + PR2;

    const float INV64 = 1.f / 64.f;

    hipLaunchKernelGGL(k_halos1, dim3(1728, 5), dim3(256), 0, stream, wsf);
    hipLaunchKernelGGL(k_meta, dim3(1), dim3(64), 0, stream, tlbrs, meta);
    hipLaunchKernelGGL(k_im2hwc, dim3(9216), dim3(256), 0, stream, images,
        (_Float16*)(wsf + IMH));

    // ---- weight banks (Kpad mult of 64) ----
    hipLaunchKernelGGL(k_wprepH, dim3(112), dim3(256), 0, stream,
        fw1, wb + WB1, 3, 49, 8, 64, 64, 28672);
    hipLaunchKernelGGL(k_wprepH, dim3(576), dim3(256), 0, stream,
        fw2, wb + WB2, 64, 9, 64, 256, 256, 147456);
    hipLaunchKernelGGL(k_wprepH, dim3(4608), dim3(256), 0, stream,
        fw3, wb + WB3, 256, 9, 256, 512, 512, 1179648);
    hipLaunchKernelGGL(k_wprepH, dim3(18432), dim3(256), 0, stream,
        fw4, wb + WB4, 512, 9, 512, 1024, 1024, 4718592);
    hipLaunchKernelGGL(k_wprepH, dim3(448), dim3(256), 0, stream,
        rw1, wb + WR1, 6, 49, 8, 196, 256, 114688);
    hipLaunchKernelGGL(k_wprepH, dim3(2528), dim3(256), 0, stream,
        rw2, wb + WR2, 196, 25, 200, 128, 128, 647168);
    hipLaunchKernelGGL(k_wprepH, dim3(288), dim3(256), 0, stream,
        rw3, wb + WR3, 128, 9, 128, 64, 64, 73728);

    // ---- backbone ----
    hipLaunchKernelGGL((k_convH<49, 7, 2, 8, 2>), dim3(288, 1, 2), dim3(256), 0, stream,
        imhI, 400, 1280000L, wb + WB1, (const float*)nullptr,
        b1hI, 208, 2768896L, 64, 64, 192, 3, 448, 64, 1.f, 1.f,
        1, 7, (float*)nullptr);
    // conv2 split-K=2
    hipLaunchKernelGGL((k_convH<9, 3, 2, 64, 2>), dim3(72, 8, 2), dim3(256), 0, stream,
        b1hI, 208, 2768896L, wb + WB2, (const float*)nullptr,
        b2hI, 112, 3211264L, 256, 256, 96, 1, 576, 256, 1.f, 1.f,
        4, 5, pconv);
    hipLaunchKernelGGL(k_redH, dim3(4608), dim3(256), 0, stream,
        pconv, 4718592L, 2, (const float*)nullptr,
        b2hI, 112, 3211264L, 96, 256, 9216, 2, 1.f, 1.f);
    // conv3 split-K=4
    hipLaunchKernelGGL((k_convH<9, 3, 2, 256, 2>), dim3(18, 32, 2), dim3(256), 0, stream,
        b2hI, 112, 3211264L, wb + WB3, (const float*)nullptr,
        f3hI, 72, 2654208L, 512, 512, 48, 1, 2304, 512, 1.f, 1.f,
        8, 9, pconv);
    hipLaunchKernelGGL(k_redH, dim3(2304), dim3(256), 0, stream,
        pconv, 2359296L, 4, (const float*)nullptr,
        f3hI, 72, 2654208L, 48, 512, 2304, 2, 1.f, 1.f);
    // conv4 split-K=4
    hipLaunchKernelGGL((k_convH<9, 3, 2, 512, 1>), dim3(9, 64, 2), dim3(256), 0, stream,
        f3hI, 72, 2654208L, wb + WB4, (const float*)nullptr,
        f4hI, 48, 2359296L, 1024, 1024, 24, 1, 4608, 1024, 1.f, 1.f,
        16, 18, pconv);
    hipLaunchKernelGGL(k_redH, dim3(1152), dim3(256), 0, stream,
        pconv, 1179648L, 4, (const float*)nullptr,
        f4hI, 48, 2359296L, 24, 1024, 576, 2, 1.f, 1.f);

    // ---- feature extraction ----
    hipLaunchKernelGGL(k_praw, dim3(1, 1024, 12), dim3(256), 0, stream,
        f3hI, f4hI, meta, wsf + PRAW);
    hipLaunchKernelGGL(k_psc, dim3(2, 1024, 36), dim3(256), 0, stream,
        wsf + PRAW, meta, wsf + PSC);
    hipLaunchKernelGGL(k_wsim, dim3(20736, 1, 4), dim3(256), 0, stream,
        wsf + PSC, meta, wsim);
    hipLaunchKernelGGL(k_fill0, dim3(203), dim3(256), 0, stream,
        wsf + SIMRAW, 51840);
    hipLaunchKernelGGL((k_simS<3, 48, 72, 512, 21, 65, false>),
        dim3(12, 32, 2), dim3(256), 0, stream,
        f3hI, 2654208L, wsim, wsf + SIMRAW);
    hipLaunchKernelGGL((k_simS<1, 24, 48, 1024, 21, 41, true>),
        dim3(9, 64, 2), dim3(256), 0, stream,
        f4hI, 2359296L, wsim, wsf + SIMRAW);
    hipLaunchKernelGGL(k_sims, dim3(432), dim3(256), 0, stream,
        wsf + SIMRAW, simshI);
    hipLaunchKernelGGL(k_halos2a, dim3(2400, 3), dim3(256), 0, stream, wsf);

    // ---- count regressor ----
    hipLaunchKernelGGL((k_convH<49, 7, 1, 8, 2>), dim3(18, 4, 6), dim3(256), 0, stream,
        simshI, 64, 32768L, wb + WR1, rb1,
        r1hI, 64, 819200L, 196, 256, 48, 3, 448, 200, 1024.f, INV64,
        4, 7, (float*)nullptr);
    hipLaunchKernelGGL(k_up2acH, dim3(5400), dim3(256), 0, stream,
        (const h8*)r1hI, 64, 102400L, (h8*)u1hI, 112, 313600L, 6, 48, 48, 25);
    // r2 split-K=2 (partials in U2H region; halo for u2 zeroed after reduce)
    hipLaunchKernelGGL((k_convH<25, 5, 1, 200, 2>), dim3(72, 4, 6), dim3(256), 0, stream,
        u1hI, 112, 2508800L, wb + WR2, rb2,
        r2h, 96, 1179648L, 128, 128, 96, 2, 5056, 128, 64.f, INV64,
        2, 40, pr2);
    hipLaunchKernelGGL(k_redH, dim3(6912), dim3(256), 0, stream,
        pr2, 7077888L, 2, rb2,
        r2h, 96, 1179648L, 96, 128, 9216, 6, 64.f, INV64);
    hipLaunchKernelGGL(k_halos2b, dim3(2400), dim3(256), 0, stream, wsf);
    hipLaunchKernelGGL(k_up2acH, dim3(13824), dim3(256), 0, stream,
        (const h8*)r2h, 96, 147456L, (h8*)u2hI, 208, 692224L, 6, 96, 96, 16);
    hipLaunchKernelGGL((k_convH<9, 3, 1, 128, 2>), dim3(288, 1, 6), dim3(256), 0, stream,
        u2hI, 208, 5537792L, wb + WR3, rb3,
        r3h, 192, 2359296L, 64, 64, 192, 1, 1152, 64, 64.f, INV64,
        1, 18, (float*)nullptr);
    hipLaunchKernelGGL(k_final, dim3(1152), dim3(256), 0, stream,
        (const h8*)r3h, rw4, rb4, rw5, rb5, out);
}